// Round 5
// baseline (340.099 us; speedup 1.0000x reference)
//
#include <hip/hip_runtime.h>

typedef unsigned short u16;
typedef unsigned int   u32;
typedef __attribute__((ext_vector_type(8))) short  short8;   // 8 x bf16
typedef __attribute__((ext_vector_type(4))) float  floatx4;

#define CNEG  (-1.4426950408889634e9f)   // -1e9 * log2(e)  (exp2 domain)
#define QSCL  (0.12753129020334545f)     // (1/sqrt(128)) * log2(e)
#define NEGF  (-1000000000.0f)           // fallback kernel (exp domain)
#define DEFER_THR 8.0f

__device__ __forceinline__ u16 f2bf(float x) {            // f32 -> bf16 RNE
  u32 u = __builtin_bit_cast(u32, x);
  u += 0x7fffu + ((u >> 16) & 1u);
  return (u16)(u >> 16);
}
__device__ __forceinline__ u32 cvtpk(float lo, float hi) { // 2xf32 -> packed bf16
  u32 r;
  asm("v_cvt_pk_bf16_f32 %0, %1, %2" : "=v"(r) : "v"(lo), "v"(hi));
  return r;
}

// swizzles (ushort index space)
__device__ __forceinline__ int swzK(int r, int c)  { return r * 128 + (c ^ ((r & 7) << 3)); }
__device__ __forceinline__ int svb(int d)          { return ((d & 7) ^ ((d >> 2) & 7)) << 3; }
__device__ __forceinline__ int swzV(int d, int kv) { return d * 64 + (kv ^ svb(d)); }

__device__ __forceinline__ void gld16(const void* g, void* l) {
  __builtin_amdgcn_global_load_lds(
      (const __attribute__((address_space(1))) u32*)g,
      (__attribute__((address_space(3))) u32*)l, 16, 0, 0);
}

constexpr int Hh = 16, Ss = 2048, Dd = 128;
constexpr int QBLK = 64, KVBLK = 64;
constexpr int NT = Ss / KVBLK;            // 32 kv tiles
constexpr int TILE = KVBLK * Dd;          // 8192 elements per tile
constexpr int NELEM = 4 * Hh * Ss * Dd;   // 16777216 per tensor
constexpr int MASKN = 4 * Ss;             // 8192 mask entries

// ---------------- prep: K/V -> bf16 pre-swizzled; mask -> float CNEG-adds ----------------
__global__ __launch_bounds__(256) void prep_kv(const float* __restrict__ K,
                                               const float* __restrict__ V,
                                               const int* __restrict__ MSK,
                                               u16* __restrict__ Kp, u16* __restrict__ Vp,
                                               float* __restrict__ Mg) {
  __shared__ u16 Vl[KVBLK * 132];
  const int blk = blockIdx.x, tid = threadIdx.x;   // blk = bh*32 + t
  const float* kg = K + (size_t)blk * TILE;
  const float* vg = V + (size_t)blk * TILE;
  u16* kp = Kp + (size_t)blk * TILE;
  u16* vp = Vp + (size_t)blk * TILE;

  if (blk < MASKN / 256) {                         // mask -> exp2-domain additive floats
    int i = blk * 256 + tid;
    Mg[i] = MSK[i] ? 0.0f : CNEG;
  }

  // K: output index j holds element (r = j>>7, c = (j&127)^swz)
  #pragma unroll
  for (int it = 0; it < 4; ++it) {
    int j = (tid + it * 256) * 8;
    int r = j >> 7, c = (j & 127) ^ ((r & 7) << 3);
    const float* s = kg + r * 128 + c;
    float4 a = *(const float4*)s, bq = *(const float4*)(s + 4);
    union { short8 v; u16 h[8]; } u;
    u.h[0] = f2bf(a.x);  u.h[1] = f2bf(a.y);  u.h[2] = f2bf(a.z);  u.h[3] = f2bf(a.w);
    u.h[4] = f2bf(bq.x); u.h[5] = f2bf(bq.y); u.h[6] = f2bf(bq.z); u.h[7] = f2bf(bq.w);
    *(short8*)(kp + j) = u.v;
  }
  // V: coalesced read -> LDS bf16, then transposed+swizzled write
  #pragma unroll
  for (int it = 0; it < 8; ++it) {
    int e = (tid + it * 256) * 4;
    int r = e >> 7, c = e & 127;
    float4 a = *(const float4*)(vg + e);
    uint2 w;
    w.x = (u32)f2bf(a.x) | ((u32)f2bf(a.y) << 16);
    w.y = (u32)f2bf(a.z) | ((u32)f2bf(a.w) << 16);
    *(uint2*)&Vl[r * 132 + c] = w;
  }
  __syncthreads();
  #pragma unroll
  for (int it = 0; it < 4; ++it) {
    int oj = (tid + it * 256) * 8;
    int d = oj >> 6, kv0 = (oj & 63) ^ svb(d);
    union { short8 v; u16 h[8]; } u;
    #pragma unroll
    for (int i = 0; i < 8; ++i) u.h[i] = Vl[(kv0 + i) * 132 + d];
    *(short8*)(vp + oj) = u.v;
  }
}

// ---------------- main: K via LDS double-buffer, V straight from L2, in-register softmax ----------------
__global__ __launch_bounds__(256, 4) void attn_fwd(const float* __restrict__ Q,
                                                   const u16* __restrict__ Kp,
                                                   const u16* __restrict__ Vp,
                                                   const float* __restrict__ Mg,
                                                   float* __restrict__ O) {
  __shared__ u16 Kl[2][TILE];              // 32 KB -> 4 blocks/CU
  __shared__ int sAff;

  const int tid = threadIdx.x, lane = tid & 63, wid = tid >> 6;
  const int l15 = lane & 15, lg = lane >> 4;
  const int id = blockIdx.x;                       // bijective XCD swizzle (2048 % 8 == 0)
  const int wg = (id & 7) * 256 + (id >> 3);
  const int bh = wg >> 5, qt = wg & 31, b = bh >> 4;
  const int qbase = qt * QBLK;
  const int qi = qbase + wid * 16 + l15;           // this lane's single q-row

  if (tid == 0) sAff = 0;

  // Q fragments (B operand): col=q=l15, k=lg*8+i
  const float* qg = Q + ((size_t)bh * Ss + qi) * Dd + lg * 8;
  short8 qf[4];
  #pragma unroll
  for (int kc = 0; kc < 4; ++kc) {
    float4 x0 = *(const float4*)(qg + kc * 32);
    float4 x1 = *(const float4*)(qg + kc * 32 + 4);
    union { short8 v; u16 h[8]; } u;
    u.h[0] = f2bf(x0.x * QSCL); u.h[1] = f2bf(x0.y * QSCL);
    u.h[2] = f2bf(x0.z * QSCL); u.h[3] = f2bf(x0.w * QSCL);
    u.h[4] = f2bf(x1.x * QSCL); u.h[5] = f2bf(x1.y * QSCL);
    u.h[6] = f2bf(x1.z * QSCL); u.h[7] = f2bf(x1.w * QSCL);
    qf[kc] = u.v;
  }

  const size_t tb = (size_t)bh * NT;
  auto stage = [&](int buf, int t) {       // K only: 4 x global_load_lds dwordx4
    const char* gk = (const char*)(Kp + (tb + t) * TILE) + wid * 4096 + lane * 16;
    char* lk = (char*)&Kl[buf][0] + wid * 4096;
    #pragma unroll
    for (int i = 0; i < 4; ++i) gld16(gk + i * 1024, lk + i * 1024);
  };

  float m_run = -3.0e38f, l_run = 0.0f;
  floatx4 oacc[8];
  const floatx4 vzero = {0.f, 0.f, 0.f, 0.f};
  #pragma unroll
  for (int dt = 0; dt < 8; ++dt) oacc[dt] = vzero;

  // bpermute byte-indices for P redistribution (computed once)
  const int idxA = (l15 + 16 * ((2 * lg) & 3)) * 4;
  const int idxB = (l15 + 16 * ((2 * lg + 1) & 3)) * 4;

  stage(0, 0);
  __syncthreads();

  int cur = 0;
  bool staged = true;
  for (int t = 0; t < NT; ++t) {
    if (t > qt && !sAff) break;            // future tiles only for the padding-quirk rows
    if (!staged) { stage(cur, t); __syncthreads(); }
    const bool pref = (t + 1 <= qt);
    if (pref) stage(cur ^ 1, t + 1);

    const int kvbase = t * KVBLK;
    const u16* vt = Vp + (tb + t) * TILE;  // V fragments read straight from global/L2
    float4 md[4];
    #pragma unroll
    for (int kt = 0; kt < 4; ++kt)
      md[kt] = *(const float4*)(Mg + b * Ss + kvbase + kt * 16 + lg * 4);

    // S^T = K . Q^T  (D[kv][q]; this lane: q=l15, kv = kvbase + kt*16 + lg*4 + r)
    floatx4 sacc[4];
    #pragma unroll
    for (int kt = 0; kt < 4; ++kt) sacc[kt] = vzero;
    __builtin_amdgcn_s_setprio(1);
    #pragma unroll
    for (int kt = 0; kt < 4; ++kt) {
      const int krow = kt * 16 + l15;
      #pragma unroll
      for (int kc = 0; kc < 4; ++kc) {
        short8 kf = *(const short8*)&Kl[cur][swzK(krow, kc * 32 + lg * 8)];
        sacc[kt] = __builtin_amdgcn_mfma_f32_16x16x32_bf16(kf, qf[kc], sacc[kt], 0, 0, 0);
      }
    }
    __builtin_amdgcn_s_setprio(0);

    // scores + masks (additive in f32, matching reference rounding)
    float p[4][4];
    #pragma unroll
    for (int kt = 0; kt < 4; ++kt) {
      p[kt][0] = sacc[kt][0] + md[kt].x;
      p[kt][1] = sacc[kt][1] + md[kt].y;
      p[kt][2] = sacc[kt][2] + md[kt].z;
      p[kt][3] = sacc[kt][3] + md[kt].w;
    }
    if (t == qt) {                         // causal only on the diagonal tile
      #pragma unroll
      for (int kt = 0; kt < 4; ++kt)
        #pragma unroll
        for (int r = 0; r < 4; ++r)
          if (kvbase + kt * 16 + lg * 4 + r > qi) p[kt][r] += CNEG;
    } else if (t > qt) {                   // quirk tiles: every col is future
      #pragma unroll
      for (int kt = 0; kt < 4; ++kt)
        #pragma unroll
        for (int r = 0; r < 4; ++r) p[kt][r] += CNEG;
    }

    // row max (per-thread tree + 2 shuffles across lg groups)
    float pmax = p[0][0];
    #pragma unroll
    for (int kt = 0; kt < 4; ++kt)
      #pragma unroll
      for (int r = 0; r < 4; ++r) pmax = fmaxf(pmax, p[kt][r]);
    pmax = fmaxf(pmax, __shfl_xor(pmax, 16, 64));
    pmax = fmaxf(pmax, __shfl_xor(pmax, 32, 64));

    // defer-max: skip O-rescale when max growth bounded (exp2 values <= 2^8)
    const bool skip = __all(pmax <= m_run + DEFER_THR);
    float mn = m_run;
    if (!skip) {
      mn = fmaxf(m_run, pmax);
      const float alpha = exp2f(m_run - mn);
      m_run = mn;
      l_run *= alpha;
      #pragma unroll
      for (int dt = 0; dt < 8; ++dt)
        #pragma unroll
        for (int r = 0; r < 4; ++r) oacc[dt][r] *= alpha;
    }

    float ps = 0.0f;
    #pragma unroll
    for (int kt = 0; kt < 4; ++kt)
      #pragma unroll
      for (int r = 0; r < 4; ++r) {
        const float pv = exp2f(p[kt][r] - mn);
        p[kt][r] = pv;
        ps += pv;
      }
    ps += __shfl_xor(ps, 16, 64);
    ps += __shfl_xor(ps, 32, 64);
    l_run += ps;

    // pack P to bf16 pairs, redistribute quads to B-fragment layout
    u32 pkw[4][2];
    #pragma unroll
    for (int kt = 0; kt < 4; ++kt) {
      pkw[kt][0] = cvtpk(p[kt][0], p[kt][1]);
      pkw[kt][1] = cvtpk(p[kt][2], p[kt][3]);
    }
    union { short8 v; u32 w[4]; } pf[2];
    #pragma unroll
    for (int kc = 0; kc < 2; ++kc) {
      #pragma unroll
      for (int wq = 0; wq < 4; ++wq) {
        const int ws = wq & 1;
        const int idx = (wq >> 1) ? idxB : idxA;
        const u32 a  = (u32)__builtin_amdgcn_ds_bpermute(idx, (int)pkw[2 * kc][ws]);
        const u32 bb = (u32)__builtin_amdgcn_ds_bpermute(idx, (int)pkw[2 * kc + 1][ws]);
        pf[kc].w[wq] = (lg & 2) ? bb : a;
      }
    }

    // O^T += V^T . P^T  (V fragments from global; this lane: q=l15, d = dt*16 + lg*4 + r)
    __builtin_amdgcn_s_setprio(1);
    #pragma unroll
    for (int kc = 0; kc < 2; ++kc) {
      #pragma unroll
      for (int dt = 0; dt < 8; ++dt) {
        short8 vf = *(const short8*)&vt[swzV(dt * 16 + l15, kc * 32 + lg * 8)];
        oacc[dt] = __builtin_amdgcn_mfma_f32_16x16x32_bf16(vf, pf[kc].v, oacc[dt], 0, 0, 0);
      }
    }
    __builtin_amdgcn_s_setprio(0);

    if (t == qt) {
      if (m_run < -1.0e9f) sAff = 1;       // fully-masked visible prefix (benign race)
    }
    __syncthreads();
    staged = pref;
    cur ^= 1;
  }

  // epilogue: O[qi][d] = oacc/l, d = dt*16 + lg*4 + r  -> float4 stores
  const float inv = 1.0f / l_run;
  float* orow = O + ((size_t)bh * Ss + qi) * Dd;
  #pragma unroll
  for (int dt = 0; dt < 8; ++dt) {
    float4 o4;
    o4.x = oacc[dt][0] * inv; o4.y = oacc[dt][1] * inv;
    o4.z = oacc[dt][2] * inv; o4.w = oacc[dt][3] * inv;
    *(float4*)(orow + dt * 16 + lg * 4) = o4;
  }
}

// ---------------- fallback (round-2 self-contained kernel) if d_ws is too small ----------------
__device__ __forceinline__ int swzPf(int row, int col) { return row * 64 + (col ^ ((row & 7) << 3)); }

__global__ __launch_bounds__(256) void attn_fb(
    const float* __restrict__ Q, const float* __restrict__ K,
    const float* __restrict__ V, const int* __restrict__ MSK,
    float* __restrict__ O)
{
  __shared__ u16 Kls[KVBLK * Dd];
  __shared__ u16 Vts[Dd * KVBLK];
  __shared__ u16 Pls[4][16 * KVBLK];
  __shared__ int sAff;

  const int tid = threadIdx.x, lane = tid & 63, wid = tid >> 6;
  const int l15 = lane & 15, lg = lane >> 4;
  const int qt = blockIdx.x, bh = blockIdx.y, b = bh >> 4;
  const int qbase = qt * QBLK;
  const float scale = 0.08838834764831845f;

  const int qrowA = qbase + wid * 16 + l15;
  const float* qg = Q + ((size_t)bh * Ss + qrowA) * Dd + lg * 8;
  short8 qf[4];
  #pragma unroll
  for (int kc = 0; kc < 4; ++kc) {
    float4 x0 = *(const float4*)(qg + kc * 32);
    float4 x1 = *(const float4*)(qg + kc * 32 + 4);
    union { short8 v; u16 h[8]; } u;
    u.h[0] = f2bf(x0.x * scale); u.h[1] = f2bf(x0.y * scale);
    u.h[2] = f2bf(x0.z * scale); u.h[3] = f2bf(x0.w * scale);
    u.h[4] = f2bf(x1.x * scale); u.h[5] = f2bf(x1.y * scale);
    u.h[6] = f2bf(x1.z * scale); u.h[7] = f2bf(x1.w * scale);
    qf[kc] = u.v;
  }

  float m_run[4], l_run[4];
  floatx4 oacc[8];
  const floatx4 vzero = {0.f, 0.f, 0.f, 0.f};
  #pragma unroll
  for (int r = 0; r < 4; ++r) { m_run[r] = -3.0e38f; l_run[r] = 0.0f; }
  #pragma unroll
  for (int dt = 0; dt < 8; ++dt) oacc[dt] = vzero;
  const int qi0 = qbase + wid * 16 + lg * 4;

  for (int t = 0; t < NT; ++t) {
    if (t > qt && !sAff) break;
    const int kvbase = t * KVBLK;
    const float* kg = K + ((size_t)bh * Ss + kvbase) * Dd;
    const float* vg = V + ((size_t)bh * Ss + kvbase) * Dd;
    #pragma unroll
    for (int it = 0; it < 8; ++it) {
      int e = (tid + it * 256) * 4;
      int r0 = e >> 7, c0 = e & 127;
      float4 x = *(const float4*)(kg + e);
      uint2 hk;
      hk.x = (u32)f2bf(x.x) | ((u32)f2bf(x.y) << 16);
      hk.y = (u32)f2bf(x.z) | ((u32)f2bf(x.w) << 16);
      *(uint2*)&Kls[swzK(r0, c0)] = hk;
      float4 y = *(const float4*)(vg + e);
      u16 hv[4] = { f2bf(y.x), f2bf(y.y), f2bf(y.z), f2bf(y.w) };
      #pragma unroll
      for (int j = 0; j < 4; ++j) Vts[swzV(c0 + j, r0)] = hv[j];
    }
    __syncthreads();

    float madd[4];
    #pragma unroll
    for (int kt = 0; kt < 4; ++kt)
      madd[kt] = MSK[b * Ss + kvbase + kt * 16 + l15] ? 0.0f : NEGF;

    floatx4 sacc[4];
    #pragma unroll
    for (int kt = 0; kt < 4; ++kt) sacc[kt] = vzero;
    #pragma unroll
    for (int kt = 0; kt < 4; ++kt) {
      const int krow = kt * 16 + l15;
      #pragma unroll
      for (int kc = 0; kc < 4; ++kc) {
        short8 kf = *(const short8*)&Kls[swzK(krow, kc * 32 + lg * 8)];
        sacc[kt] = __builtin_amdgcn_mfma_f32_16x16x32_bf16(qf[kc], kf, sacc[kt], 0, 0, 0);
      }
    }

    float mnew[4];
    #pragma unroll
    for (int r = 0; r < 4; ++r) mnew[r] = m_run[r];
    #pragma unroll
    for (int kt = 0; kt < 4; ++kt) {
      const int kvj = kvbase + kt * 16 + l15;
      #pragma unroll
      for (int r = 0; r < 4; ++r) {
        float s = sacc[kt][r] + madd[kt];
        if (kvj > qi0 + r) s += NEGF;
        sacc[kt][r] = s;
        mnew[r] = fmaxf(mnew[r], s);
      }
    }
    #pragma unroll
    for (int off = 1; off < 16; off <<= 1) {
      #pragma unroll
      for (int r = 0; r < 4; ++r)
        mnew[r] = fmaxf(mnew[r], __shfl_xor(mnew[r], off, 64));
    }
    float alpha[4], psum[4];
    #pragma unroll
    for (int r = 0; r < 4; ++r) {
      alpha[r] = __expf(m_run[r] - mnew[r]);
      m_run[r] = mnew[r];
      psum[r] = 0.f;
    }
    #pragma unroll
    for (int kt = 0; kt < 4; ++kt) {
      #pragma unroll
      for (int r = 0; r < 4; ++r) {
        float p = __expf(sacc[kt][r] - mnew[r]);
        psum[r] += p;
        Pls[wid][swzPf(lg * 4 + r, kt * 16 + l15)] = f2bf(p);
      }
    }
    #pragma unroll
    for (int off = 1; off < 16; off <<= 1) {
      #pragma unroll
      for (int r = 0; r < 4; ++r)
        psum[r] += __shfl_xor(psum[r], off, 64);
    }
    #pragma unroll
    for (int r = 0; r < 4; ++r) l_run[r] = l_run[r] * alpha[r] + psum[r];
    #pragma unroll
    for (int dt = 0; dt < 8; ++dt) {
      #pragma unroll
      for (int r = 0; r < 4; ++r) oacc[dt][r] *= alpha[r];
    }
    #pragma unroll
    for (int kc = 0; kc < 2; ++kc) {
      short8 pfr = *(const short8*)&Pls[wid][swzPf(l15, kc * 32 + lg * 8)];
      #pragma unroll
      for (int dt = 0; dt < 8; ++dt) {
        short8 vf = *(const short8*)&Vts[swzV(dt * 16 + l15, kc * 32 + lg * 8)];
        oacc[dt] = __builtin_amdgcn_mfma_f32_16x16x32_bf16(pfr, vf, oacc[dt], 0, 0, 0);
      }
    }
    __syncthreads();

    if (t == qt) {
      if (tid == 0) sAff = 0;
      __syncthreads();
      bool aff = (m_run[0] < -5.0e8f) || (m_run[1] < -5.0e8f) ||
                 (m_run[2] < -5.0e8f) || (m_run[3] < -5.0e8f);
      if (aff) sAff = 1;
      __syncthreads();
    }
  }

  #pragma unroll
  for (int r = 0; r < 4; ++r) {
    float inv = 1.0f / l_run[r];
    float* op = O + ((size_t)bh * Ss + qi0 + r) * Dd + l15;
    #pragma unroll
    for (int dt = 0; dt < 8; ++dt) op[dt * 16] = oacc[dt][r] * inv;
  }
}

extern "C" void kernel_launch(void* const* d_in, const int* in_sizes, int n_in,
                              void* d_out, int out_size, void* d_ws, size_t ws_size,
                              hipStream_t stream) {
  const float* q = (const float*)d_in[0];
  const float* k = (const float*)d_in[1];
  const float* v = (const float*)d_in[2];
  const int* mask = (const int*)d_in[3];
  float* out = (float*)d_out;

  const size_t need = (size_t)2 * NELEM * sizeof(u16) + (size_t)MASKN * sizeof(float);
  if (ws_size >= need) {
    u16* Kp = (u16*)d_ws;
    u16* Vp = Kp + NELEM;
    float* Mg = (float*)(Vp + NELEM);
    prep_kv<<<dim3(64 * NT), 256, 0, stream>>>(k, v, mask, Kp, Vp, Mg);
    attn_fwd<<<dim3(2048), 256, 0, stream>>>(q, Kp, Vp, Mg, out);
  } else {
    attn_fb<<<dim3(NT, 64), 256, 0, stream>>>(q, k, v, mask, out);
  }
}

// Round 6
// 241.355 us; speedup vs baseline: 1.4091x; 1.4091x over previous
//
#include <hip/hip_runtime.h>

typedef unsigned short u16;
typedef unsigned int   u32;
typedef __attribute__((ext_vector_type(8))) short  short8;   // 8 x bf16
typedef __attribute__((ext_vector_type(4))) float  floatx4;

#define CNEG  (-1.4426950408889634e9f)   // -1e9 * log2(e)  (exp2 domain)
#define QSCL  (0.12753129020334545f)     // (1/sqrt(128)) * log2(e)
#define NEGF  (-1000000000.0f)           // fallback kernel (exp domain)
#define DEFER_THR 8.0f

__device__ __forceinline__ u16 f2bf(float x) {            // f32 -> bf16 RNE
  u32 u = __builtin_bit_cast(u32, x);
  u += 0x7fffu + ((u >> 16) & 1u);
  return (u16)(u >> 16);
}
__device__ __forceinline__ u32 cvtpk(float lo, float hi) { // 2xf32 -> packed bf16
  u32 r;
  asm("v_cvt_pk_bf16_f32 %0, %1, %2" : "=v"(r) : "v"(lo), "v"(hi));
  return r;
}

// swizzles (ushort index space)
__device__ __forceinline__ int swzK(int r, int c)  { return r * 128 + (c ^ ((r & 7) << 3)); }
__device__ __forceinline__ int svb(int d)          { return ((d & 7) ^ ((d >> 2) & 7)) << 3; }
__device__ __forceinline__ int swzV(int d, int kv) { return d * 64 + (kv ^ svb(d)); }

__device__ __forceinline__ void gld16(const void* g, void* l) {
  __builtin_amdgcn_global_load_lds(
      (const __attribute__((address_space(1))) u32*)g,
      (__attribute__((address_space(3))) u32*)l, 16, 0, 0);
}

constexpr int Hh = 16, Ss = 2048, Dd = 128;
constexpr int QBLK = 128, KVBLK = 64;     // 8 waves x 16 q-rows
constexpr int NT = Ss / KVBLK;            // 32 kv tiles
constexpr int NQT = Ss / QBLK;            // 16 q tiles
constexpr int TILE = KVBLK * Dd;          // 8192 elements per tile
constexpr int NELEM = 4 * Hh * Ss * Dd;   // 16777216 per tensor
constexpr int MASKN = 4 * Ss;             // 8192 mask entries

// ---------------- prep: K/V -> bf16 pre-swizzled; mask -> float CNEG-adds ----------------
__global__ __launch_bounds__(256) void prep_kv(const float* __restrict__ K,
                                               const float* __restrict__ V,
                                               const int* __restrict__ MSK,
                                               u16* __restrict__ Kp, u16* __restrict__ Vp,
                                               float* __restrict__ Mg) {
  __shared__ u16 Vl[KVBLK * 132];
  const int blk = blockIdx.x, tid = threadIdx.x;   // blk = bh*32 + t
  const float* kg = K + (size_t)blk * TILE;
  const float* vg = V + (size_t)blk * TILE;
  u16* kp = Kp + (size_t)blk * TILE;
  u16* vp = Vp + (size_t)blk * TILE;

  if (blk < MASKN / 256) {                         // mask -> exp2-domain additive floats
    int i = blk * 256 + tid;
    Mg[i] = MSK[i] ? 0.0f : CNEG;
  }

  // K: output index j holds element (r = j>>7, c = (j&127)^swz)
  #pragma unroll
  for (int it = 0; it < 4; ++it) {
    int j = (tid + it * 256) * 8;
    int r = j >> 7, c = (j & 127) ^ ((r & 7) << 3);
    const float* s = kg + r * 128 + c;
    float4 a = *(const float4*)s, bq = *(const float4*)(s + 4);
    union { short8 v; u16 h[8]; } u;
    u.h[0] = f2bf(a.x);  u.h[1] = f2bf(a.y);  u.h[2] = f2bf(a.z);  u.h[3] = f2bf(a.w);
    u.h[4] = f2bf(bq.x); u.h[5] = f2bf(bq.y); u.h[6] = f2bf(bq.z); u.h[7] = f2bf(bq.w);
    *(short8*)(kp + j) = u.v;
  }
  // V: coalesced read -> LDS bf16, then transposed+swizzled write
  #pragma unroll
  for (int it = 0; it < 8; ++it) {
    int e = (tid + it * 256) * 4;
    int r = e >> 7, c = e & 127;
    float4 a = *(const float4*)(vg + e);
    uint2 w;
    w.x = (u32)f2bf(a.x) | ((u32)f2bf(a.y) << 16);
    w.y = (u32)f2bf(a.z) | ((u32)f2bf(a.w) << 16);
    *(uint2*)&Vl[r * 132 + c] = w;
  }
  __syncthreads();
  #pragma unroll
  for (int it = 0; it < 4; ++it) {
    int oj = (tid + it * 256) * 8;
    int d = oj >> 6, kv0 = (oj & 63) ^ svb(d);
    union { short8 v; u16 h[8]; } u;
    #pragma unroll
    for (int i = 0; i < 8; ++i) u.h[i] = Vl[(kv0 + i) * 132 + d];
    *(short8*)(vp + oj) = u.v;
  }
}

// ---------------- main: 8 waves / 128 q-rows, K+V LDS double-buffer, in-register softmax ----------------
__global__ __launch_bounds__(512, 4) void attn_fwd(const float* __restrict__ Q,
                                                   const u16* __restrict__ Kp,
                                                   const u16* __restrict__ Vp,
                                                   const float* __restrict__ Mg,
                                                   float* __restrict__ O) {
  __shared__ u16 Kl[2][TILE];              // 32 KB
  __shared__ u16 Vt[2][TILE];              // 32 KB -> 64KB total, 2 blocks/CU, 16 waves/CU
  __shared__ int sAff;

  const int tid = threadIdx.x, lane = tid & 63, wid = tid >> 6;
  const int l15 = lane & 15, lg = lane >> 4;
  const int id = blockIdx.x;                       // bijective XCD swizzle (1024 % 8 == 0)
  const int wg = (id & 7) * 128 + (id >> 3);
  const int bh = wg >> 4, qt = wg & 15, b = bh >> 4;
  const int qbase = qt * QBLK;
  const int qi = qbase + wid * 16 + l15;           // this lane's single q-row
  const int dtl = 2 * qt + 1;                      // last causal kv-tile for this block

  if (tid == 0) sAff = 0;

  // Q fragments (B operand): col=q=l15, k=lg*8+i
  const float* qg = Q + ((size_t)bh * Ss + qi) * Dd + lg * 8;
  short8 qf[4];
  #pragma unroll
  for (int kc = 0; kc < 4; ++kc) {
    float4 x0 = *(const float4*)(qg + kc * 32);
    float4 x1 = *(const float4*)(qg + kc * 32 + 4);
    union { short8 v; u16 h[8]; } u;
    u.h[0] = f2bf(x0.x * QSCL); u.h[1] = f2bf(x0.y * QSCL);
    u.h[2] = f2bf(x0.z * QSCL); u.h[3] = f2bf(x0.w * QSCL);
    u.h[4] = f2bf(x1.x * QSCL); u.h[5] = f2bf(x1.y * QSCL);
    u.h[6] = f2bf(x1.z * QSCL); u.h[7] = f2bf(x1.w * QSCL);
    qf[kc] = u.v;
  }

  const size_t tb = (size_t)bh * NT;
  auto stage = [&](int buf, int t) {       // 8 waves cover 16KB K + 16KB V: 4 gld16/thread
    const char* gk = (const char*)(Kp + (tb + t) * TILE) + wid * 1024 + lane * 16;
    const char* gv = (const char*)(Vp + (tb + t) * TILE) + wid * 1024 + lane * 16;
    char* lk = (char*)&Kl[buf][0] + wid * 1024;    // wave-uniform dest base
    char* lv = (char*)&Vt[buf][0] + wid * 1024;
    #pragma unroll
    for (int i = 0; i < 2; ++i) {
      gld16(gk + i * 8192, lk + i * 8192);
      gld16(gv + i * 8192, lv + i * 8192);
    }
  };

  float m_run = -3.0e38f, l_run = 0.0f;
  floatx4 oacc[8];
  const floatx4 vzero = {0.f, 0.f, 0.f, 0.f};
  #pragma unroll
  for (int dt = 0; dt < 8; ++dt) oacc[dt] = vzero;

  // bpermute byte-indices for P redistribution (computed once)
  const int idxA = (l15 + 16 * ((2 * lg) & 3)) * 4;
  const int idxB = (l15 + 16 * ((2 * lg + 1) & 3)) * 4;

  stage(0, 0);
  __syncthreads();

  int cur = 0;
  bool staged = true;
  for (int t = 0; t < NT; ++t) {
    if (t > dtl && !sAff) break;           // future tiles only for the padding-quirk rows
    if (!staged) { stage(cur, t); __syncthreads(); }
    const bool pref = (t + 1 <= dtl);
    if (pref) stage(cur ^ 1, t + 1);

    const int kvbase = t * KVBLK;
    float4 md[4];
    #pragma unroll
    for (int kt = 0; kt < 4; ++kt)
      md[kt] = *(const float4*)(Mg + b * Ss + kvbase + kt * 16 + lg * 4);

    // S^T = K . Q^T  (D[kv][q]; this lane: q=l15, kv = kvbase + kt*16 + lg*4 + r)
    floatx4 sacc[4];
    #pragma unroll
    for (int kt = 0; kt < 4; ++kt) sacc[kt] = vzero;
    __builtin_amdgcn_s_setprio(1);
    #pragma unroll
    for (int kt = 0; kt < 4; ++kt) {
      const int krow = kt * 16 + l15;
      #pragma unroll
      for (int kc = 0; kc < 4; ++kc) {
        short8 kf = *(const short8*)&Kl[cur][swzK(krow, kc * 32 + lg * 8)];
        sacc[kt] = __builtin_amdgcn_mfma_f32_16x16x32_bf16(kf, qf[kc], sacc[kt], 0, 0, 0);
      }
    }
    __builtin_amdgcn_s_setprio(0);

    // scores + masks (additive in f32, matching reference rounding)
    float p[4][4];
    #pragma unroll
    for (int kt = 0; kt < 4; ++kt) {
      p[kt][0] = sacc[kt][0] + md[kt].x;
      p[kt][1] = sacc[kt][1] + md[kt].y;
      p[kt][2] = sacc[kt][2] + md[kt].z;
      p[kt][3] = sacc[kt][3] + md[kt].w;
    }
    // causal: wave-uniform skip when tile fully visible for this wave's 16 rows;
    // per-element adds cover diagonal AND fully-future (quirk) tiles uniformly
    if (kvbase + KVBLK - 1 >= qbase + wid * 16) {
      #pragma unroll
      for (int kt = 0; kt < 4; ++kt)
        #pragma unroll
        for (int r = 0; r < 4; ++r)
          if (kvbase + kt * 16 + lg * 4 + r > qi) p[kt][r] += CNEG;
    }

    // row max (per-thread tree + 2 shuffles across lg groups)
    float pmax = p[0][0];
    #pragma unroll
    for (int kt = 0; kt < 4; ++kt)
      #pragma unroll
      for (int r = 0; r < 4; ++r) pmax = fmaxf(pmax, p[kt][r]);
    pmax = fmaxf(pmax, __shfl_xor(pmax, 16, 64));
    pmax = fmaxf(pmax, __shfl_xor(pmax, 32, 64));

    // defer-max: skip O-rescale when max growth bounded (exp2 values <= 2^8)
    const bool skip = __all(pmax <= m_run + DEFER_THR);
    float mn = m_run;
    if (!skip) {
      mn = fmaxf(m_run, pmax);
      const float alpha = exp2f(m_run - mn);
      m_run = mn;
      l_run *= alpha;
      #pragma unroll
      for (int dt = 0; dt < 8; ++dt)
        #pragma unroll
        for (int r = 0; r < 4; ++r) oacc[dt][r] *= alpha;
    }

    float ps = 0.0f;
    #pragma unroll
    for (int kt = 0; kt < 4; ++kt)
      #pragma unroll
      for (int r = 0; r < 4; ++r) {
        const float pv = exp2f(p[kt][r] - mn);
        p[kt][r] = pv;
        ps += pv;
      }
    ps += __shfl_xor(ps, 16, 64);
    ps += __shfl_xor(ps, 32, 64);
    l_run += ps;

    // pack P to bf16 pairs, redistribute quads to B-fragment layout
    u32 pkw[4][2];
    #pragma unroll
    for (int kt = 0; kt < 4; ++kt) {
      pkw[kt][0] = cvtpk(p[kt][0], p[kt][1]);
      pkw[kt][1] = cvtpk(p[kt][2], p[kt][3]);
    }
    union { short8 v; u32 w[4]; } pf[2];
    #pragma unroll
    for (int kc = 0; kc < 2; ++kc) {
      #pragma unroll
      for (int wq = 0; wq < 4; ++wq) {
        const int ws = wq & 1;
        const int idx = (wq >> 1) ? idxB : idxA;
        const u32 a  = (u32)__builtin_amdgcn_ds_bpermute(idx, (int)pkw[2 * kc][ws]);
        const u32 bb = (u32)__builtin_amdgcn_ds_bpermute(idx, (int)pkw[2 * kc + 1][ws]);
        pf[kc].w[wq] = (lg & 2) ? bb : a;
      }
    }

    // O^T += V^T . P^T  (D[d][q]; this lane: q=l15, d = dt*16 + lg*4 + r)
    __builtin_amdgcn_s_setprio(1);
    #pragma unroll
    for (int kc = 0; kc < 2; ++kc) {
      #pragma unroll
      for (int dt = 0; dt < 8; ++dt) {
        short8 vf = *(const short8*)&Vt[cur][swzV(dt * 16 + l15, kc * 32 + lg * 8)];
        oacc[dt] = __builtin_amdgcn_mfma_f32_16x16x32_bf16(vf, pf[kc].v, oacc[dt], 0, 0, 0);
      }
    }
    __builtin_amdgcn_s_setprio(0);

    if (t == dtl) {
      if (m_run < -1.0e9f) sAff = 1;       // fully-masked visible prefix (benign race)
    }
    __syncthreads();
    staged = pref;
    cur ^= 1;
  }

  // epilogue: O[qi][d] = oacc/l, d = dt*16 + lg*4 + r  -> float4 stores
  const float inv = 1.0f / l_run;
  float* orow = O + ((size_t)bh * Ss + qi) * Dd;
  #pragma unroll
  for (int dt = 0; dt < 8; ++dt) {
    float4 o4;
    o4.x = oacc[dt][0] * inv; o4.y = oacc[dt][1] * inv;
    o4.z = oacc[dt][2] * inv; o4.w = oacc[dt][3] * inv;
    *(float4*)(orow + dt * 16 + lg * 4) = o4;
  }
}

// ---------------- fallback (round-2 self-contained kernel) if d_ws is too small ----------------
__device__ __forceinline__ int swzPf(int row, int col) { return row * 64 + (col ^ ((row & 7) << 3)); }

__global__ __launch_bounds__(256) void attn_fb(
    const float* __restrict__ Q, const float* __restrict__ K,
    const float* __restrict__ V, const int* __restrict__ MSK,
    float* __restrict__ O)
{
  __shared__ u16 Kls[KVBLK * Dd];
  __shared__ u16 Vts[Dd * KVBLK];
  __shared__ u16 Pls[4][16 * KVBLK];
  __shared__ int sAff;

  const int tid = threadIdx.x, lane = tid & 63, wid = tid >> 6;
  const int l15 = lane & 15, lg = lane >> 4;
  const int qt = blockIdx.x, bh = blockIdx.y, b = bh >> 4;
  const int qbase = qt * 64;
  const float scale = 0.08838834764831845f;

  const int qrowA = qbase + wid * 16 + l15;
  const float* qg = Q + ((size_t)bh * Ss + qrowA) * Dd + lg * 8;
  short8 qf[4];
  #pragma unroll
  for (int kc = 0; kc < 4; ++kc) {
    float4 x0 = *(const float4*)(qg + kc * 32);
    float4 x1 = *(const float4*)(qg + kc * 32 + 4);
    union { short8 v; u16 h[8]; } u;
    u.h[0] = f2bf(x0.x * scale); u.h[1] = f2bf(x0.y * scale);
    u.h[2] = f2bf(x0.z * scale); u.h[3] = f2bf(x0.w * scale);
    u.h[4] = f2bf(x1.x * scale); u.h[5] = f2bf(x1.y * scale);
    u.h[6] = f2bf(x1.z * scale); u.h[7] = f2bf(x1.w * scale);
    qf[kc] = u.v;
  }

  float m_run[4], l_run[4];
  floatx4 oacc[8];
  const floatx4 vzero = {0.f, 0.f, 0.f, 0.f};
  #pragma unroll
  for (int r = 0; r < 4; ++r) { m_run[r] = -3.0e38f; l_run[r] = 0.0f; }
  #pragma unroll
  for (int dt = 0; dt < 8; ++dt) oacc[dt] = vzero;
  const int qi0 = qbase + wid * 16 + lg * 4;

  for (int t = 0; t < NT; ++t) {
    if (t > blockIdx.x && !sAff) break;
    const int kvbase = t * KVBLK;
    const float* kg = K + ((size_t)bh * Ss + kvbase) * Dd;
    const float* vg = V + ((size_t)bh * Ss + kvbase) * Dd;
    #pragma unroll
    for (int it = 0; it < 8; ++it) {
      int e = (tid + it * 256) * 4;
      int r0 = e >> 7, c0 = e & 127;
      float4 x = *(const float4*)(kg + e);
      uint2 hk;
      hk.x = (u32)f2bf(x.x) | ((u32)f2bf(x.y) << 16);
      hk.y = (u32)f2bf(x.z) | ((u32)f2bf(x.w) << 16);
      *(uint2*)&Kls[swzK(r0, c0)] = hk;
      float4 y = *(const float4*)(vg + e);
      u16 hv[4] = { f2bf(y.x), f2bf(y.y), f2bf(y.z), f2bf(y.w) };
      #pragma unroll
      for (int j = 0; j < 4; ++j) Vts[swzV(c0 + j, r0)] = hv[j];
    }
    __syncthreads();

    float madd[4];
    #pragma unroll
    for (int kt = 0; kt < 4; ++kt)
      madd[kt] = MSK[b * Ss + kvbase + kt * 16 + l15] ? 0.0f : NEGF;

    floatx4 sacc[4];
    #pragma unroll
    for (int kt = 0; kt < 4; ++kt) sacc[kt] = vzero;
    #pragma unroll
    for (int kt = 0; kt < 4; ++kt) {
      const int krow = kt * 16 + l15;
      #pragma unroll
      for (int kc = 0; kc < 4; ++kc) {
        short8 kf = *(const short8*)&Kls[swzK(krow, kc * 32 + lg * 8)];
        sacc[kt] = __builtin_amdgcn_mfma_f32_16x16x32_bf16(qf[kc], kf, sacc[kt], 0, 0, 0);
      }
    }

    float mnew[4];
    #pragma unroll
    for (int r = 0; r < 4; ++r) mnew[r] = m_run[r];
    #pragma unroll
    for (int kt = 0; kt < 4; ++kt) {
      const int kvj = kvbase + kt * 16 + l15;
      #pragma unroll
      for (int r = 0; r < 4; ++r) {
        float s = sacc[kt][r] + madd[kt];
        if (kvj > qi0 + r) s += NEGF;
        sacc[kt][r] = s;
        mnew[r] = fmaxf(mnew[r], s);
      }
    }
    #pragma unroll
    for (int off = 1; off < 16; off <<= 1) {
      #pragma unroll
      for (int r = 0; r < 4; ++r)
        mnew[r] = fmaxf(mnew[r], __shfl_xor(mnew[r], off, 64));
    }
    float alpha[4], psum[4];
    #pragma unroll
    for (int r = 0; r < 4; ++r) {
      alpha[r] = __expf(m_run[r] - mnew[r]);
      m_run[r] = mnew[r];
      psum[r] = 0.f;
    }
    #pragma unroll
    for (int kt = 0; kt < 4; ++kt) {
      #pragma unroll
      for (int r = 0; r < 4; ++r) {
        float p = __expf(sacc[kt][r] - mnew[r]);
        psum[r] += p;
        Pls[wid][swzPf(lg * 4 + r, kt * 16 + l15)] = f2bf(p);
      }
    }
    #pragma unroll
    for (int off = 1; off < 16; off <<= 1) {
      #pragma unroll
      for (int r = 0; r < 4; ++r)
        psum[r] += __shfl_xor(psum[r], off, 64);
    }
    #pragma unroll
    for (int r = 0; r < 4; ++r) l_run[r] = l_run[r] * alpha[r] + psum[r];
    #pragma unroll
    for (int dt = 0; dt < 8; ++dt) {
      #pragma unroll
      for (int r = 0; r < 4; ++r) oacc[dt][r] *= alpha[r];
    }
    #pragma unroll
    for (int kc = 0; kc < 2; ++kc) {
      short8 pfr = *(const short8*)&Pls[wid][swzPf(l15, kc * 32 + lg * 8)];
      #pragma unroll
      for (int dt = 0; dt < 8; ++dt) {
        short8 vf = *(const short8*)&Vts[swzV(dt * 16 + l15, kc * 32 + lg * 8)];
        oacc[dt] = __builtin_amdgcn_mfma_f32_16x16x32_bf16(pfr, vf, oacc[dt], 0, 0, 0);
      }
    }
    __syncthreads();

    if (t == blockIdx.x) {
      if (tid == 0) sAff = 0;
      __syncthreads();
      bool aff = (m_run[0] < -5.0e8f) || (m_run[1] < -5.0e8f) ||
                 (m_run[2] < -5.0e8f) || (m_run[3] < -5.0e8f);
      if (aff) sAff = 1;
      __syncthreads();
    }
  }

  #pragma unroll
  for (int r = 0; r < 4; ++r) {
    float inv = 1.0f / l_run[r];
    float* op = O + ((size_t)bh * Ss + qi0 + r) * Dd + l15;
    #pragma unroll
    for (int dt = 0; dt < 8; ++dt) op[dt * 16] = oacc[dt][r] * inv;
  }
}

extern "C" void kernel_launch(void* const* d_in, const int* in_sizes, int n_in,
                              void* d_out, int out_size, void* d_ws, size_t ws_size,
                              hipStream_t stream) {
  const float* q = (const float*)d_in[0];
  const float* k = (const float*)d_in[1];
  const float* v = (const float*)d_in[2];
  const int* mask = (const int*)d_in[3];
  float* out = (float*)d_out;

  const size_t need = (size_t)2 * NELEM * sizeof(u16) + (size_t)MASKN * sizeof(float);
  if (ws_size >= need) {
    u16* Kp = (u16*)d_ws;
    u16* Vp = Kp + NELEM;
    float* Mg = (float*)(Vp + NELEM);
    prep_kv<<<dim3(64 * NT), 256, 0, stream>>>(k, v, mask, Kp, Vp, Mg);
    attn_fwd<<<dim3(64 * NQT), 512, 0, stream>>>(q, Kp, Vp, Mg, out);
  } else {
    attn_fb<<<dim3(NT, 64), 256, 0, stream>>>(q, k, v, mask, out);
  }
}

// Round 7
// 240.993 us; speedup vs baseline: 1.4112x; 1.0015x over previous
//
#include <hip/hip_runtime.h>

typedef unsigned short u16;
typedef unsigned int   u32;
typedef __attribute__((ext_vector_type(8))) short  short8;   // 8 x bf16
typedef __attribute__((ext_vector_type(4))) float  floatx4;

#define CNEG  (-1.4426950408889634e9f)   // -1e9 * log2(e)  (exp2 domain)
#define QSCL  (0.12753129020334545f)     // (1/sqrt(128)) * log2(e)
#define NEGF  (-1000000000.0f)           // fallback kernel (exp domain)
#define DEFER_THR 8.0f

__device__ __forceinline__ u16 f2bf(float x) {            // f32 -> bf16 RNE
  u32 u = __builtin_bit_cast(u32, x);
  u += 0x7fffu + ((u >> 16) & 1u);
  return (u16)(u >> 16);
}
__device__ __forceinline__ u32 cvtpk(float lo, float hi) { // 2xf32 -> packed bf16
  u32 r;
  asm("v_cvt_pk_bf16_f32 %0, %1, %2" : "=v"(r) : "v"(lo), "v"(hi));
  return r;
}

// swizzles (ushort index space)
__device__ __forceinline__ int swzK(int r, int c)  { return r * 128 + (c ^ ((r & 7) << 3)); }
__device__ __forceinline__ int svb(int d)          { return ((d & 7) ^ ((d >> 2) & 7)) << 3; }
__device__ __forceinline__ int swzV(int d, int kv) { return d * 64 + (kv ^ svb(d)); }

__device__ __forceinline__ void gld16(const void* g, void* l) {
  __builtin_amdgcn_global_load_lds(
      (const __attribute__((address_space(1))) u32*)g,
      (__attribute__((address_space(3))) u32*)l, 16, 0, 0);
}

constexpr int Hh = 16, Ss = 2048, Dd = 128;
constexpr int QBLK = 128, KVBLK = 64;     // 8 waves x 16 q-rows
constexpr int NT = Ss / KVBLK;            // 32 kv tiles
constexpr int NQT = Ss / QBLK;            // 16 q tiles
constexpr int TILE = KVBLK * Dd;          // 8192 elements per tile
constexpr int NELEM = 4 * Hh * Ss * Dd;   // 16777216 per tensor
constexpr int MASKN = 4 * Ss;             // 8192 mask entries

// ---------------- prep: K/V -> bf16 pre-swizzled; mask -> float CNEG-adds ----------------
__global__ __launch_bounds__(256) void prep_kv(const float* __restrict__ K,
                                               const float* __restrict__ V,
                                               const int* __restrict__ MSK,
                                               u16* __restrict__ Kp, u16* __restrict__ Vp,
                                               float* __restrict__ Mg) {
  __shared__ u16 Vl[KVBLK * 132];
  const int blk = blockIdx.x, tid = threadIdx.x;   // blk = bh*32 + t
  const float* kg = K + (size_t)blk * TILE;
  const float* vg = V + (size_t)blk * TILE;
  u16* kp = Kp + (size_t)blk * TILE;
  u16* vp = Vp + (size_t)blk * TILE;

  if (blk < MASKN / 256) {                         // mask -> exp2-domain additive floats
    int i = blk * 256 + tid;
    Mg[i] = MSK[i] ? 0.0f : CNEG;
  }

  // K: output index j holds element (r = j>>7, c = (j&127)^swz)
  #pragma unroll
  for (int it = 0; it < 4; ++it) {
    int j = (tid + it * 256) * 8;
    int r = j >> 7, c = (j & 127) ^ ((r & 7) << 3);
    const float* s = kg + r * 128 + c;
    float4 a = *(const float4*)s, bq = *(const float4*)(s + 4);
    union { short8 v; u16 h[8]; } u;
    u.h[0] = f2bf(a.x);  u.h[1] = f2bf(a.y);  u.h[2] = f2bf(a.z);  u.h[3] = f2bf(a.w);
    u.h[4] = f2bf(bq.x); u.h[5] = f2bf(bq.y); u.h[6] = f2bf(bq.z); u.h[7] = f2bf(bq.w);
    *(short8*)(kp + j) = u.v;
  }
  // V: coalesced read -> LDS bf16, then transposed+swizzled write
  #pragma unroll
  for (int it = 0; it < 8; ++it) {
    int e = (tid + it * 256) * 4;
    int r = e >> 7, c = e & 127;
    float4 a = *(const float4*)(vg + e);
    uint2 w;
    w.x = (u32)f2bf(a.x) | ((u32)f2bf(a.y) << 16);
    w.y = (u32)f2bf(a.z) | ((u32)f2bf(a.w) << 16);
    *(uint2*)&Vl[r * 132 + c] = w;
  }
  __syncthreads();
  #pragma unroll
  for (int it = 0; it < 4; ++it) {
    int oj = (tid + it * 256) * 8;
    int d = oj >> 6, kv0 = (oj & 63) ^ svb(d);
    union { short8 v; u16 h[8]; } u;
    #pragma unroll
    for (int i = 0; i < 8; ++i) u.h[i] = Vl[(kv0 + i) * 132 + d];
    *(short8*)(vp + oj) = u.v;
  }
}

// ---------------- main: 8 waves / 128 q-rows, K+V LDS double-buffer, in-register softmax ----------------
__global__ __launch_bounds__(512, 4) void attn_fwd(const float* __restrict__ Q,
                                                   const u16* __restrict__ Kp,
                                                   const u16* __restrict__ Vp,
                                                   const float* __restrict__ Mg,
                                                   float* __restrict__ O) {
  __shared__ u16 Kl[2][TILE];              // 32 KB
  __shared__ u16 Vt[2][TILE];              // 32 KB -> 64KB total, 2 blocks/CU, 16 waves/CU
  __shared__ int sAff;

  const int tid = threadIdx.x, lane = tid & 63, wid = tid >> 6;
  const int l15 = lane & 15, lg = lane >> 4;
  const int id = blockIdx.x;                       // bijective XCD swizzle (1024 % 8 == 0)
  const int wg = (id & 7) * 128 + (id >> 3);
  const int bh = wg >> 4, qt = wg & 15, b = bh >> 4;
  const int qbase = qt * QBLK;
  const int qi = qbase + wid * 16 + l15;           // this lane's single q-row
  const int dtl = 2 * qt + 1;                      // last causal kv-tile for this block

  if (tid == 0) sAff = 0;

  // Q fragments (B operand): col=q=l15, k=lg*8+i
  const float* qg = Q + ((size_t)bh * Ss + qi) * Dd + lg * 8;
  short8 qf[4];
  #pragma unroll
  for (int kc = 0; kc < 4; ++kc) {
    float4 x0 = *(const float4*)(qg + kc * 32);
    float4 x1 = *(const float4*)(qg + kc * 32 + 4);
    union { short8 v; u16 h[8]; } u;
    u.h[0] = f2bf(x0.x * QSCL); u.h[1] = f2bf(x0.y * QSCL);
    u.h[2] = f2bf(x0.z * QSCL); u.h[3] = f2bf(x0.w * QSCL);
    u.h[4] = f2bf(x1.x * QSCL); u.h[5] = f2bf(x1.y * QSCL);
    u.h[6] = f2bf(x1.z * QSCL); u.h[7] = f2bf(x1.w * QSCL);
    qf[kc] = u.v;
  }

  const size_t tb = (size_t)bh * NT;
  auto stage = [&](int buf, int t) {       // 8 waves cover 16KB K + 16KB V: 4 gld16/thread
    const char* gk = (const char*)(Kp + (tb + t) * TILE) + wid * 1024 + lane * 16;
    const char* gv = (const char*)(Vp + (tb + t) * TILE) + wid * 1024 + lane * 16;
    char* lk = (char*)&Kl[buf][0] + wid * 1024;    // wave-uniform dest base
    char* lv = (char*)&Vt[buf][0] + wid * 1024;
    #pragma unroll
    for (int i = 0; i < 2; ++i) {
      gld16(gk + i * 8192, lk + i * 8192);
      gld16(gv + i * 8192, lv + i * 8192);
    }
  };

  float m_run = -3.0e38f, l_run = 0.0f;
  floatx4 oacc[8];
  const floatx4 vzero = {0.f, 0.f, 0.f, 0.f};
  #pragma unroll
  for (int dt = 0; dt < 8; ++dt) oacc[dt] = vzero;

  // bpermute byte-indices for P redistribution (computed once)
  const int idxA = (l15 + 16 * ((2 * lg) & 3)) * 4;
  const int idxB = (l15 + 16 * ((2 * lg + 1) & 3)) * 4;

  stage(0, 0);
  __syncthreads();

  int cur = 0;
  bool staged = true;
  for (int t = 0; t < NT; ++t) {
    if (t > dtl && !sAff) break;           // future tiles only for the padding-quirk rows
    if (!staged) { stage(cur, t); __syncthreads(); }
    const bool pref = (t + 1 <= dtl);
    if (pref) stage(cur ^ 1, t + 1);

    const int kvbase = t * KVBLK;
    float4 md[4];
    #pragma unroll
    for (int kt = 0; kt < 4; ++kt)
      md[kt] = *(const float4*)(Mg + b * Ss + kvbase + kt * 16 + lg * 4);

    // S^T = K . Q^T  (D[kv][q]; this lane: q=l15, kv = kvbase + kt*16 + lg*4 + r)
    floatx4 sacc[4];
    #pragma unroll
    for (int kt = 0; kt < 4; ++kt) sacc[kt] = vzero;
    __builtin_amdgcn_s_setprio(1);
    #pragma unroll
    for (int kt = 0; kt < 4; ++kt) {
      const int krow = kt * 16 + l15;
      #pragma unroll
      for (int kc = 0; kc < 4; ++kc) {
        short8 kf = *(const short8*)&Kl[cur][swzK(krow, kc * 32 + lg * 8)];
        sacc[kt] = __builtin_amdgcn_mfma_f32_16x16x32_bf16(kf, qf[kc], sacc[kt], 0, 0, 0);
      }
    }
    __builtin_amdgcn_s_setprio(0);

    // scores + masks (additive in f32, matching reference rounding)
    float p[4][4];
    #pragma unroll
    for (int kt = 0; kt < 4; ++kt) {
      p[kt][0] = sacc[kt][0] + md[kt].x;
      p[kt][1] = sacc[kt][1] + md[kt].y;
      p[kt][2] = sacc[kt][2] + md[kt].z;
      p[kt][3] = sacc[kt][3] + md[kt].w;
    }
    // causal: wave-uniform skip when tile fully visible for this wave's 16 rows;
    // per-element adds cover diagonal AND fully-future (quirk) tiles uniformly
    if (kvbase + KVBLK - 1 >= qbase + wid * 16) {
      #pragma unroll
      for (int kt = 0; kt < 4; ++kt)
        #pragma unroll
        for (int r = 0; r < 4; ++r)
          if (kvbase + kt * 16 + lg * 4 + r > qi) p[kt][r] += CNEG;
    }

    // row max (per-thread tree + 2 shuffles across lg groups)
    float pmax = p[0][0];
    #pragma unroll
    for (int kt = 0; kt < 4; ++kt)
      #pragma unroll
      for (int r = 0; r < 4; ++r) pmax = fmaxf(pmax, p[kt][r]);
    pmax = fmaxf(pmax, __shfl_xor(pmax, 16, 64));
    pmax = fmaxf(pmax, __shfl_xor(pmax, 32, 64));

    // defer-max: skip O-rescale when max growth bounded (exp2 values <= 2^8)
    const bool skip = __all(pmax <= m_run + DEFER_THR);
    float mn = m_run;
    if (!skip) {
      mn = fmaxf(m_run, pmax);
      const float alpha = exp2f(m_run - mn);
      m_run = mn;
      l_run *= alpha;
      #pragma unroll
      for (int dt = 0; dt < 8; ++dt)
        #pragma unroll
        for (int r = 0; r < 4; ++r) oacc[dt][r] *= alpha;
    }

    float ps = 0.0f;
    #pragma unroll
    for (int kt = 0; kt < 4; ++kt)
      #pragma unroll
      for (int r = 0; r < 4; ++r) {
        const float pv = exp2f(p[kt][r] - mn);
        p[kt][r] = pv;
        ps += pv;
      }
    ps += __shfl_xor(ps, 16, 64);
    ps += __shfl_xor(ps, 32, 64);
    l_run += ps;

    // pack P to bf16 pairs, redistribute quads to B-fragment layout
    u32 pkw[4][2];
    #pragma unroll
    for (int kt = 0; kt < 4; ++kt) {
      pkw[kt][0] = cvtpk(p[kt][0], p[kt][1]);
      pkw[kt][1] = cvtpk(p[kt][2], p[kt][3]);
    }
    union { short8 v; u32 w[4]; } pf[2];
    #pragma unroll
    for (int kc = 0; kc < 2; ++kc) {
      #pragma unroll
      for (int wq = 0; wq < 4; ++wq) {
        const int ws = wq & 1;
        const int idx = (wq >> 1) ? idxB : idxA;
        const u32 a  = (u32)__builtin_amdgcn_ds_bpermute(idx, (int)pkw[2 * kc][ws]);
        const u32 bb = (u32)__builtin_amdgcn_ds_bpermute(idx, (int)pkw[2 * kc + 1][ws]);
        pf[kc].w[wq] = (lg & 2) ? bb : a;
      }
    }

    // O^T += V^T . P^T  (D[d][q]; this lane: q=l15, d = dt*16 + lg*4 + r)
    __builtin_amdgcn_s_setprio(1);
    #pragma unroll
    for (int kc = 0; kc < 2; ++kc) {
      #pragma unroll
      for (int dt = 0; dt < 8; ++dt) {
        short8 vf = *(const short8*)&Vt[cur][swzV(dt * 16 + l15, kc * 32 + lg * 8)];
        oacc[dt] = __builtin_amdgcn_mfma_f32_16x16x32_bf16(vf, pf[kc].v, oacc[dt], 0, 0, 0);
      }
    }
    __builtin_amdgcn_s_setprio(0);

    if (t == dtl) {
      if (m_run < -1.0e9f) sAff = 1;       // fully-masked visible prefix (benign race)
    }
    __syncthreads();
    staged = pref;
    cur ^= 1;
  }

  // epilogue: O[qi][d] = oacc/l, d = dt*16 + lg*4 + r  -> float4 stores
  const float inv = 1.0f / l_run;
  float* orow = O + ((size_t)bh * Ss + qi) * Dd;
  #pragma unroll
  for (int dt = 0; dt < 8; ++dt) {
    float4 o4;
    o4.x = oacc[dt][0] * inv; o4.y = oacc[dt][1] * inv;
    o4.z = oacc[dt][2] * inv; o4.w = oacc[dt][3] * inv;
    *(float4*)(orow + dt * 16 + lg * 4) = o4;
  }
}

// ---------------- fallback (round-2 self-contained kernel) if d_ws is too small ----------------
__device__ __forceinline__ int swzPf(int row, int col) { return row * 64 + (col ^ ((row & 7) << 3)); }

__global__ __launch_bounds__(256) void attn_fb(
    const float* __restrict__ Q, const float* __restrict__ K,
    const float* __restrict__ V, const int* __restrict__ MSK,
    float* __restrict__ O)
{
  __shared__ u16 Kls[KVBLK * Dd];
  __shared__ u16 Vts[Dd * KVBLK];
  __shared__ u16 Pls[4][16 * KVBLK];
  __shared__ int sAff;

  const int tid = threadIdx.x, lane = tid & 63, wid = tid >> 6;
  const int l15 = lane & 15, lg = lane >> 4;
  const int qt = blockIdx.x, bh = blockIdx.y, b = bh >> 4;
  const int qbase = qt * 64;
  const float scale = 0.08838834764831845f;

  const int qrowA = qbase + wid * 16 + l15;
  const float* qg = Q + ((size_t)bh * Ss + qrowA) * Dd + lg * 8;
  short8 qf[4];
  #pragma unroll
  for (int kc = 0; kc < 4; ++kc) {
    float4 x0 = *(const float4*)(qg + kc * 32);
    float4 x1 = *(const float4*)(qg + kc * 32 + 4);
    union { short8 v; u16 h[8]; } u;
    u.h[0] = f2bf(x0.x * scale); u.h[1] = f2bf(x0.y * scale);
    u.h[2] = f2bf(x0.z * scale); u.h[3] = f2bf(x0.w * scale);
    u.h[4] = f2bf(x1.x * scale); u.h[5] = f2bf(x1.y * scale);
    u.h[6] = f2bf(x1.z * scale); u.h[7] = f2bf(x1.w * scale);
    qf[kc] = u.v;
  }

  float m_run[4], l_run[4];
  floatx4 oacc[8];
  const floatx4 vzero = {0.f, 0.f, 0.f, 0.f};
  #pragma unroll
  for (int r = 0; r < 4; ++r) { m_run[r] = -3.0e38f; l_run[r] = 0.0f; }
  #pragma unroll
  for (int dt = 0; dt < 8; ++dt) oacc[dt] = vzero;
  const int qi0 = qbase + wid * 16 + lg * 4;

  for (int t = 0; t < NT; ++t) {
    if (t > blockIdx.x && !sAff) break;
    const int kvbase = t * KVBLK;
    const float* kg = K + ((size_t)bh * Ss + kvbase) * Dd;
    const float* vg = V + ((size_t)bh * Ss + kvbase) * Dd;
    #pragma unroll
    for (int it = 0; it < 8; ++it) {
      int e = (tid + it * 256) * 4;
      int r0 = e >> 7, c0 = e & 127;
      float4 x = *(const float4*)(kg + e);
      uint2 hk;
      hk.x = (u32)f2bf(x.x) | ((u32)f2bf(x.y) << 16);
      hk.y = (u32)f2bf(x.z) | ((u32)f2bf(x.w) << 16);
      *(uint2*)&Kls[swzK(r0, c0)] = hk;
      float4 y = *(const float4*)(vg + e);
      u16 hv[4] = { f2bf(y.x), f2bf(y.y), f2bf(y.z), f2bf(y.w) };
      #pragma unroll
      for (int j = 0; j < 4; ++j) Vts[swzV(c0 + j, r0)] = hv[j];
    }
    __syncthreads();

    float madd[4];
    #pragma unroll
    for (int kt = 0; kt < 4; ++kt)
      madd[kt] = MSK[b * Ss + kvbase + kt * 16 + l15] ? 0.0f : NEGF;

    floatx4 sacc[4];
    #pragma unroll
    for (int kt = 0; kt < 4; ++kt) sacc[kt] = vzero;
    #pragma unroll
    for (int kt = 0; kt < 4; ++kt) {
      const int krow = kt * 16 + l15;
      #pragma unroll
      for (int kc = 0; kc < 4; ++kc) {
        short8 kf = *(const short8*)&Kls[swzK(krow, kc * 32 + lg * 8)];
        sacc[kt] = __builtin_amdgcn_mfma_f32_16x16x32_bf16(qf[kc], kf, sacc[kt], 0, 0, 0);
      }
    }

    float mnew[4];
    #pragma unroll
    for (int r = 0; r < 4; ++r) mnew[r] = m_run[r];
    #pragma unroll
    for (int kt = 0; kt < 4; ++kt) {
      const int kvj = kvbase + kt * 16 + l15;
      #pragma unroll
      for (int r = 0; r < 4; ++r) {
        float s = sacc[kt][r] + madd[kt];
        if (kvj > qi0 + r) s += NEGF;
        sacc[kt][r] = s;
        mnew[r] = fmaxf(mnew[r], s);
      }
    }
    #pragma unroll
    for (int off = 1; off < 16; off <<= 1) {
      #pragma unroll
      for (int r = 0; r < 4; ++r)
        mnew[r] = fmaxf(mnew[r], __shfl_xor(mnew[r], off, 64));
    }
    float alpha[4], psum[4];
    #pragma unroll
    for (int r = 0; r < 4; ++r) {
      alpha[r] = __expf(m_run[r] - mnew[r]);
      m_run[r] = mnew[r];
      psum[r] = 0.f;
    }
    #pragma unroll
    for (int kt = 0; kt < 4; ++kt) {
      #pragma unroll
      for (int r = 0; r < 4; ++r) {
        float p = __expf(sacc[kt][r] - mnew[r]);
        psum[r] += p;
        Pls[wid][swzPf(lg * 4 + r, kt * 16 + l15)] = f2bf(p);
      }
    }
    #pragma unroll
    for (int off = 1; off < 16; off <<= 1) {
      #pragma unroll
      for (int r = 0; r < 4; ++r)
        psum[r] += __shfl_xor(psum[r], off, 64);
    }
    #pragma unroll
    for (int r = 0; r < 4; ++r) l_run[r] = l_run[r] * alpha[r] + psum[r];
    #pragma unroll
    for (int dt = 0; dt < 8; ++dt) {
      #pragma unroll
      for (int r = 0; r < 4; ++r) oacc[dt][r] *= alpha[r];
    }
    #pragma unroll
    for (int kc = 0; kc < 2; ++kc) {
      short8 pfr = *(const short8*)&Pls[wid][swzPf(l15, kc * 32 + lg * 8)];
      #pragma unroll
      for (int dt = 0; dt < 8; ++dt) {
        short8 vf = *(const short8*)&Vts[swzV(dt * 16 + l15, kc * 32 + lg * 8)];
        oacc[dt] = __builtin_amdgcn_mfma_f32_16x16x32_bf16(pfr, vf, oacc[dt], 0, 0, 0);
      }
    }
    __syncthreads();

    if (t == blockIdx.x) {
      if (tid == 0) sAff = 0;
      __syncthreads();
      bool aff = (m_run[0] < -5.0e8f) || (m_run[1] < -5.0e8f) ||
                 (m_run[2] < -5.0e8f) || (m_run[3] < -5.0e8f);
      if (aff) sAff = 1;
      __syncthreads();
    }
  }

  #pragma unroll
  for (int r = 0; r < 4; ++r) {
    float inv = 1.0f / l_run[r];
    float* op = O + ((size_t)bh * Ss + qi0 + r) * Dd + l15;
    #pragma unroll
    for (int dt = 0; dt < 8; ++dt) op[dt * 16] = oacc[dt][r] * inv;
  }
}

extern "C" void kernel_launch(void* const* d_in, const int* in_sizes, int n_in,
                              void* d_out, int out_size, void* d_ws, size_t ws_size,
                              hipStream_t stream) {
  const float* q = (const float*)d_in[0];
  const float* k = (const float*)d_in[1];
  const float* v = (const float*)d_in[2];
  const int* mask = (const int*)d_in[3];
  float* out = (float*)d_out;

  const size_t need = (size_t)2 * NELEM * sizeof(u16) + (size_t)MASKN * sizeof(float);
  if (ws_size >= need) {
    u16* Kp = (u16*)d_ws;
    u16* Vp = Kp + NELEM;
    float* Mg = (float*)(Vp + NELEM);
    prep_kv<<<dim3(64 * NT), 256, 0, stream>>>(k, v, mask, Kp, Vp, Mg);
    attn_fwd<<<dim3(64 * NQT), 512, 0, stream>>>(q, Kp, Vp, Mg, out);
  } else {
    attn_fb<<<dim3(NT, 64), 256, 0, stream>>>(q, k, v, mask, out);
  }
}

// Round 8
// 212.055 us; speedup vs baseline: 1.6038x; 1.1365x over previous
//
#include <hip/hip_runtime.h>

typedef unsigned short u16;
typedef unsigned int   u32;
typedef __attribute__((ext_vector_type(8))) short  short8;   // 8 x bf16
typedef __attribute__((ext_vector_type(4))) float  floatx4;

#define CNEG  (-1.4426950408889634e9f)   // -1e9 * log2(e)  (exp2 domain)
#define QSCL  (0.12753129020334545f)     // (1/sqrt(128)) * log2(e)
#define NEGF  (-1000000000.0f)           // fallback kernel (exp domain)
#define DEFER_THR 8.0f

__device__ __forceinline__ u16 f2bf(float x) {            // f32 -> bf16 RNE
  u32 u = __builtin_bit_cast(u32, x);
  u += 0x7fffu + ((u >> 16) & 1u);
  return (u16)(u >> 16);
}
__device__ __forceinline__ u32 cvtpk(float lo, float hi) { // 2xf32 -> packed bf16
  u32 r;
  asm("v_cvt_pk_bf16_f32 %0, %1, %2" : "=v"(r) : "v"(lo), "v"(hi));
  return r;
}

// swizzles (ushort index space)
__device__ __forceinline__ int swzK(int r, int c)  { return r * 128 + (c ^ ((r & 7) << 3)); }
__device__ __forceinline__ int svb(int d)          { return ((d & 7) ^ ((d >> 2) & 7)) << 3; }
__device__ __forceinline__ int swzV(int d, int kv) { return d * 64 + (kv ^ svb(d)); }
// K-row permutation: slot -> source kv.  bits [b5 b4 | b3 b2 | b1 b0] -> [b5 | b3 b2 | b4 | b1 b0]
// Makes QK's C/D quads coincide with PV's K=32 B-fragment layout (no cross-lane redistribution).
__device__ __forceinline__ int sigma(int r) {
  return (r & 0x20) | ((r & 0xC) << 1) | ((r & 0x10) >> 2) | (r & 3);
}

__device__ __forceinline__ void gld16(const void* g, void* l) {
  __builtin_amdgcn_global_load_lds(
      (const __attribute__((address_space(1))) u32*)g,
      (__attribute__((address_space(3))) u32*)l, 16, 0, 0);
}

constexpr int Hh = 16, Ss = 2048, Dd = 128;
constexpr int QBLK = 128, KVBLK = 64;     // 8 waves x 16 q-rows
constexpr int NT = Ss / KVBLK;            // 32 kv tiles
constexpr int NQT = Ss / QBLK;            // 16 q tiles
constexpr int TILE = KVBLK * Dd;          // 8192 elements per tile
constexpr int NELEM = 4 * Hh * Ss * Dd;   // 16777216 per tensor
constexpr int MASKN = 4 * Ss;             // 8192 mask entries

// ---------------- prep: K -> bf16 sigma-permuted+swizzled tiles; V -> bf16 fragment-linear ----------------
__global__ __launch_bounds__(256) void prep_kv(const float* __restrict__ K,
                                               const float* __restrict__ V,
                                               const int* __restrict__ MSK,
                                               u16* __restrict__ Kp, u16* __restrict__ Vp,
                                               float* __restrict__ Mg) {
  __shared__ u16 Vl[KVBLK * 132];
  const int blk = blockIdx.x, tid = threadIdx.x;   // blk = bh*32 + t
  const float* kg = K + (size_t)blk * TILE;
  const float* vg = V + (size_t)blk * TILE;
  u16* kp = Kp + (size_t)blk * TILE;
  u16* vp = Vp + (size_t)blk * TILE;

  if (blk < MASKN / 256) {                         // mask -> exp2-domain additive floats
    int i = blk * 256 + tid;
    Mg[i] = MSK[i] ? 0.0f : CNEG;
  }

  // K: slot row r holds source kv row sigma(r), column-XOR-swizzled (as main reads swzK(slot,.))
  #pragma unroll
  for (int it = 0; it < 4; ++it) {
    int j = (tid + it * 256) * 8;
    int r = j >> 7;                                // tile row slot
    int rp = sigma(r);                             // source kv row
    int c = (j & 127) ^ ((r & 7) << 3);            // bits 0-2 intact -> 8-contig run
    const float* s = kg + rp * 128 + c;
    float4 a = *(const float4*)s, bq = *(const float4*)(s + 4);
    union { short8 v; u16 h[8]; } u;
    u.h[0] = f2bf(a.x);  u.h[1] = f2bf(a.y);  u.h[2] = f2bf(a.z);  u.h[3] = f2bf(a.w);
    u.h[4] = f2bf(bq.x); u.h[5] = f2bf(bq.y); u.h[6] = f2bf(bq.z); u.h[7] = f2bf(bq.w);
    *(short8*)(kp + j) = u.v;
  }
  // V: coalesced read -> LDS bf16 [kv][d]
  #pragma unroll
  for (int it = 0; it < 8; ++it) {
    int e = (tid + it * 256) * 4;
    int r = e >> 7, c = e & 127;
    float4 a = *(const float4*)(vg + e);
    uint2 w;
    w.x = (u32)f2bf(a.x) | ((u32)f2bf(a.y) << 16);
    w.y = (u32)f2bf(a.z) | ((u32)f2bf(a.w) << 16);
    *(uint2*)&Vl[r * 132 + c] = w;
  }
  __syncthreads();
  // V out: fragment-linear.  frag f = (dt*2+kc)*64 + lane; lane(l15,lg) holds
  // V^T[dt*16+l15][kc*32 + lg*8 + i], i=0..7  ->  main reads b128 at lane*16B + seg*1024B.
  #pragma unroll
  for (int it = 0; it < 4; ++it) {
    int f = tid + it * 256;              // 0..1023
    int ln = f & 63, seg = f >> 6;       // seg = dt*2 + kc
    int kc = seg & 1, dt = seg >> 1;
    int d = dt * 16 + (ln & 15);
    int kv0 = kc * 32 + (ln >> 4) * 8;
    union { short8 v; u16 h[8]; } u;
    #pragma unroll
    for (int i = 0; i < 8; ++i) u.h[i] = Vl[(kv0 + i) * 132 + d];
    *(short8*)(vp + f * 8) = u.v;
  }
}

// ---------------- main: 8 waves / 128 q-rows, K+V LDS double-buffer, zero-shuffle softmax->PV ----------------
__global__ __launch_bounds__(512, 4) void attn_fwd(const float* __restrict__ Q,
                                                   const u16* __restrict__ Kp,
                                                   const u16* __restrict__ Vp,
                                                   const float* __restrict__ Mg,
                                                   float* __restrict__ O) {
  __shared__ u16 Kl[2][TILE];              // 32 KB
  __shared__ u16 Vt[2][TILE];              // 32 KB -> 64KB total, 2 blocks/CU, 16 waves/CU
  __shared__ int sAff;

  const int tid = threadIdx.x, lane = tid & 63, wid = tid >> 6;
  const int l15 = lane & 15, lg = lane >> 4;
  const int id = blockIdx.x;                       // bijective XCD swizzle (1024 % 8 == 0)
  const int wg = (id & 7) * 128 + (id >> 3);
  const int bh = wg >> 4, qt = wg & 15, b = bh >> 4;
  const int qbase = qt * QBLK;
  const int qi = qbase + wid * 16 + l15;           // this lane's single q-row
  const int dtl = 2 * qt + 1;                      // last causal kv-tile for this block

  if (tid == 0) sAff = 0;

  // Q fragments (B operand): col=q=l15, k=lg*8+i
  const float* qg = Q + ((size_t)bh * Ss + qi) * Dd + lg * 8;
  short8 qf[4];
  #pragma unroll
  for (int kc = 0; kc < 4; ++kc) {
    float4 x0 = *(const float4*)(qg + kc * 32);
    float4 x1 = *(const float4*)(qg + kc * 32 + 4);
    union { short8 v; u16 h[8]; } u;
    u.h[0] = f2bf(x0.x * QSCL); u.h[1] = f2bf(x0.y * QSCL);
    u.h[2] = f2bf(x0.z * QSCL); u.h[3] = f2bf(x0.w * QSCL);
    u.h[4] = f2bf(x1.x * QSCL); u.h[5] = f2bf(x1.y * QSCL);
    u.h[6] = f2bf(x1.z * QSCL); u.h[7] = f2bf(x1.w * QSCL);
    qf[kc] = u.v;
  }

  const size_t tb = (size_t)bh * NT;
  auto stage = [&](int buf, int t) {       // 8 waves cover 16KB K + 16KB V: 4 gld16/thread
    const char* gk = (const char*)(Kp + (tb + t) * TILE) + wid * 1024 + lane * 16;
    const char* gv = (const char*)(Vp + (tb + t) * TILE) + wid * 1024 + lane * 16;
    char* lk = (char*)&Kl[buf][0] + wid * 1024;    // wave-uniform dest base
    char* lv = (char*)&Vt[buf][0] + wid * 1024;
    #pragma unroll
    for (int i = 0; i < 2; ++i) {
      gld16(gk + i * 8192, lk + i * 8192);
      gld16(gv + i * 8192, lv + i * 8192);
    }
  };

  float m_run = -3.0e38f, l_run = 0.0f;
  floatx4 oacc[8];
  const floatx4 vzero = {0.f, 0.f, 0.f, 0.f};
  #pragma unroll
  for (int dt = 0; dt < 8; ++dt) oacc[dt] = vzero;

  stage(0, 0);
  __syncthreads();

  int cur = 0;
  bool staged = true;
  for (int t = 0; t < NT; ++t) {
    if (t > dtl && !sAff) break;           // future tiles only for the padding-quirk rows
    if (!staged) { stage(cur, t); __syncthreads(); }
    const bool pref = (t + 1 <= dtl);
    if (pref) stage(cur ^ 1, t + 1);

    const int kvbase = t * KVBLK;
    // slot (kt,lg,r) holds score for kv = kvbase + 32*(kt>>1) + lg*8 + 4*(kt&1) + r
    float4 md[4];
    #pragma unroll
    for (int kt = 0; kt < 4; ++kt) {
      const int kvs = kvbase + ((kt >> 1) << 5) + lg * 8 + ((kt & 1) << 2);
      md[kt] = *(const float4*)(Mg + b * Ss + kvs);
    }

    // S^T = K . Q^T  (D[slot][q]; q=l15)
    floatx4 sacc[4];
    #pragma unroll
    for (int kt = 0; kt < 4; ++kt) sacc[kt] = vzero;
    __builtin_amdgcn_s_setprio(1);
    #pragma unroll
    for (int kt = 0; kt < 4; ++kt) {
      const int krow = kt * 16 + l15;
      #pragma unroll
      for (int kc = 0; kc < 4; ++kc) {
        short8 kf = *(const short8*)&Kl[cur][swzK(krow, kc * 32 + lg * 8)];
        sacc[kt] = __builtin_amdgcn_mfma_f32_16x16x32_bf16(kf, qf[kc], sacc[kt], 0, 0, 0);
      }
    }
    __builtin_amdgcn_s_setprio(0);

    // scores + masks (additive in f32, matching reference rounding)
    float p[4][4];
    #pragma unroll
    for (int kt = 0; kt < 4; ++kt) {
      p[kt][0] = sacc[kt][0] + md[kt].x;
      p[kt][1] = sacc[kt][1] + md[kt].y;
      p[kt][2] = sacc[kt][2] + md[kt].z;
      p[kt][3] = sacc[kt][3] + md[kt].w;
    }
    // causal: wave-uniform skip when tile fully visible for this wave's 16 rows;
    // per-element adds cover diagonal AND fully-future (quirk) tiles uniformly
    if (kvbase + KVBLK - 1 >= qbase + wid * 16) {
      #pragma unroll
      for (int kt = 0; kt < 4; ++kt) {
        const int kvs = kvbase + ((kt >> 1) << 5) + lg * 8 + ((kt & 1) << 2);
        #pragma unroll
        for (int r = 0; r < 4; ++r)
          if (kvs + r > qi) p[kt][r] += CNEG;
      }
    }

    // row max (per-thread tree + 2 shuffles across lg groups)
    float pmax = p[0][0];
    #pragma unroll
    for (int kt = 0; kt < 4; ++kt)
      #pragma unroll
      for (int r = 0; r < 4; ++r) pmax = fmaxf(pmax, p[kt][r]);
    pmax = fmaxf(pmax, __shfl_xor(pmax, 16, 64));
    pmax = fmaxf(pmax, __shfl_xor(pmax, 32, 64));

    // defer-max: skip O-rescale when max growth bounded (exp2 values <= 2^8)
    const bool skip = __all(pmax <= m_run + DEFER_THR);
    float mn = m_run;
    if (!skip) {
      mn = fmaxf(m_run, pmax);
      const float alpha = exp2f(m_run - mn);
      m_run = mn;
      l_run *= alpha;
      #pragma unroll
      for (int dt = 0; dt < 8; ++dt)
        #pragma unroll
        for (int r = 0; r < 4; ++r) oacc[dt][r] *= alpha;
    }

    float ps = 0.0f;
    #pragma unroll
    for (int kt = 0; kt < 4; ++kt)
      #pragma unroll
      for (int r = 0; r < 4; ++r) {
        const float pv = exp2f(p[kt][r] - mn);
        p[kt][r] = pv;
        ps += pv;
      }
    ps += __shfl_xor(ps, 16, 64);
    ps += __shfl_xor(ps, 32, 64);
    l_run += ps;

    // P fragments: sigma-permuted K rows make sacc quads pack DIRECTLY into the
    // K=32 B-operand layout — 8 cvt_pk, no cross-lane redistribution.
    union { short8 v; u32 w[4]; } pf[2];
    #pragma unroll
    for (int kc = 0; kc < 2; ++kc) {
      pf[kc].w[0] = cvtpk(p[2 * kc][0],     p[2 * kc][1]);
      pf[kc].w[1] = cvtpk(p[2 * kc][2],     p[2 * kc][3]);
      pf[kc].w[2] = cvtpk(p[2 * kc + 1][0], p[2 * kc + 1][1]);
      pf[kc].w[3] = cvtpk(p[2 * kc + 1][2], p[2 * kc + 1][3]);
    }

    // O^T += V^T . P^T ; V fragment-linear: base + immediate offsets, conflict-free b128
    const u16* vbase = &Vt[cur][lane * 8];
    __builtin_amdgcn_s_setprio(1);
    #pragma unroll
    for (int kc = 0; kc < 2; ++kc) {
      #pragma unroll
      for (int dt = 0; dt < 8; ++dt) {
        short8 vf = *(const short8*)&vbase[(dt * 2 + kc) * 512];
        oacc[dt] = __builtin_amdgcn_mfma_f32_16x16x32_bf16(vf, pf[kc].v, oacc[dt], 0, 0, 0);
      }
    }
    __builtin_amdgcn_s_setprio(0);

    if (t == dtl) {
      if (m_run < -1.0e9f) sAff = 1;       // fully-masked visible prefix (benign race)
    }
    __syncthreads();
    staged = pref;
    cur ^= 1;
  }

  // epilogue: O[qi][d] = oacc/l, d = dt*16 + lg*4 + r  -> float4 stores
  const float inv = 1.0f / l_run;
  float* orow = O + ((size_t)bh * Ss + qi) * Dd;
  #pragma unroll
  for (int dt = 0; dt < 8; ++dt) {
    float4 o4;
    o4.x = oacc[dt][0] * inv; o4.y = oacc[dt][1] * inv;
    o4.z = oacc[dt][2] * inv; o4.w = oacc[dt][3] * inv;
    *(float4*)(orow + dt * 16 + lg * 4) = o4;
  }
}

// ---------------- fallback (round-2 self-contained kernel) if d_ws is too small ----------------
__device__ __forceinline__ int swzPf(int row, int col) { return row * 64 + (col ^ ((row & 7) << 3)); }

__global__ __launch_bounds__(256) void attn_fb(
    const float* __restrict__ Q, const float* __restrict__ K,
    const float* __restrict__ V, const int* __restrict__ MSK,
    float* __restrict__ O)
{
  __shared__ u16 Kls[KVBLK * Dd];
  __shared__ u16 Vts[Dd * KVBLK];
  __shared__ u16 Pls[4][16 * KVBLK];
  __shared__ int sAff;

  const int tid = threadIdx.x, lane = tid & 63, wid = tid >> 6;
  const int l15 = lane & 15, lg = lane >> 4;
  const int qt = blockIdx.x, bh = blockIdx.y, b = bh >> 4;
  const int qbase = qt * 64;
  const float scale = 0.08838834764831845f;

  const int qrowA = qbase + wid * 16 + l15;
  const float* qg = Q + ((size_t)bh * Ss + qrowA) * Dd + lg * 8;
  short8 qf[4];
  #pragma unroll
  for (int kc = 0; kc < 4; ++kc) {
    float4 x0 = *(const float4*)(qg + kc * 32);
    float4 x1 = *(const float4*)(qg + kc * 32 + 4);
    union { short8 v; u16 h[8]; } u;
    u.h[0] = f2bf(x0.x * scale); u.h[1] = f2bf(x0.y * scale);
    u.h[2] = f2bf(x0.z * scale); u.h[3] = f2bf(x0.w * scale);
    u.h[4] = f2bf(x1.x * scale); u.h[5] = f2bf(x1.y * scale);
    u.h[6] = f2bf(x1.z * scale); u.h[7] = f2bf(x1.w * scale);
    qf[kc] = u.v;
  }

  float m_run[4], l_run[4];
  floatx4 oacc[8];
  const floatx4 vzero = {0.f, 0.f, 0.f, 0.f};
  #pragma unroll
  for (int r = 0; r < 4; ++r) { m_run[r] = -3.0e38f; l_run[r] = 0.0f; }
  #pragma unroll
  for (int dt = 0; dt < 8; ++dt) oacc[dt] = vzero;
  const int qi0 = qbase + wid * 16 + lg * 4;

  for (int t = 0; t < NT; ++t) {
    if (t > blockIdx.x && !sAff) break;
    const int kvbase = t * KVBLK;
    const float* kg = K + ((size_t)bh * Ss + kvbase) * Dd;
    const float* vg = V + ((size_t)bh * Ss + kvbase) * Dd;
    #pragma unroll
    for (int it = 0; it < 8; ++it) {
      int e = (tid + it * 256) * 4;
      int r0 = e >> 7, c0 = e & 127;
      float4 x = *(const float4*)(kg + e);
      uint2 hk;
      hk.x = (u32)f2bf(x.x) | ((u32)f2bf(x.y) << 16);
      hk.y = (u32)f2bf(x.z) | ((u32)f2bf(x.w) << 16);
      *(uint2*)&Kls[swzK(r0, c0)] = hk;
      float4 y = *(const float4*)(vg + e);
      u16 hv[4] = { f2bf(y.x), f2bf(y.y), f2bf(y.z), f2bf(y.w) };
      #pragma unroll
      for (int j = 0; j < 4; ++j) Vts[swzV(c0 + j, r0)] = hv[j];
    }
    __syncthreads();

    float madd[4];
    #pragma unroll
    for (int kt = 0; kt < 4; ++kt)
      madd[kt] = MSK[b * Ss + kvbase + kt * 16 + l15] ? 0.0f : NEGF;

    floatx4 sacc[4];
    #pragma unroll
    for (int kt = 0; kt < 4; ++kt) sacc[kt] = vzero;
    #pragma unroll
    for (int kt = 0; kt < 4; ++kt) {
      const int krow = kt * 16 + l15;
      #pragma unroll
      for (int kc = 0; kc < 4; ++kc) {
        short8 kf = *(const short8*)&Kls[swzK(krow, kc * 32 + lg * 8)];
        sacc[kt] = __builtin_amdgcn_mfma_f32_16x16x32_bf16(qf[kc], kf, sacc[kt], 0, 0, 0);
      }
    }

    float mnew[4];
    #pragma unroll
    for (int r = 0; r < 4; ++r) mnew[r] = m_run[r];
    #pragma unroll
    for (int kt = 0; kt < 4; ++kt) {
      const int kvj = kvbase + kt * 16 + l15;
      #pragma unroll
      for (int r = 0; r < 4; ++r) {
        float s = sacc[kt][r] + madd[kt];
        if (kvj > qi0 + r) s += NEGF;
        sacc[kt][r] = s;
        mnew[r] = fmaxf(mnew[r], s);
      }
    }
    #pragma unroll
    for (int off = 1; off < 16; off <<= 1) {
      #pragma unroll
      for (int r = 0; r < 4; ++r)
        mnew[r] = fmaxf(mnew[r], __shfl_xor(mnew[r], off, 64));
    }
    float alpha[4], psum[4];
    #pragma unroll
    for (int r = 0; r < 4; ++r) {
      alpha[r] = __expf(m_run[r] - mnew[r]);
      m_run[r] = mnew[r];
      psum[r] = 0.f;
    }
    #pragma unroll
    for (int kt = 0; kt < 4; ++kt) {
      #pragma unroll
      for (int r = 0; r < 4; ++r) {
        float p = __expf(sacc[kt][r] - mnew[r]);
        psum[r] += p;
        Pls[wid][swzPf(lg * 4 + r, kt * 16 + l15)] = f2bf(p);
      }
    }
    #pragma unroll
    for (int off = 1; off < 16; off <<= 1) {
      #pragma unroll
      for (int r = 0; r < 4; ++r)
        psum[r] += __shfl_xor(psum[r], off, 64);
    }
    #pragma unroll
    for (int r = 0; r < 4; ++r) l_run[r] = l_run[r] * alpha[r] + psum[r];
    #pragma unroll
    for (int dt = 0; dt < 8; ++dt) {
      #pragma unroll
      for (int r = 0; r < 4; ++r) oacc[dt][r] *= alpha[r];
    }
    #pragma unroll
    for (int kc = 0; kc < 2; ++kc) {
      short8 pfr = *(const short8*)&Pls[wid][swzPf(l15, kc * 32 + lg * 8)];
      #pragma unroll
      for (int dt = 0; dt < 8; ++dt) {
        short8 vf = *(const short8*)&Vts[swzV(dt * 16 + l15, kc * 32 + lg * 8)];
        oacc[dt] = __builtin_amdgcn_mfma_f32_16x16x32_bf16(pfr, vf, oacc[dt], 0, 0, 0);
      }
    }
    __syncthreads();

    if (t == blockIdx.x) {
      if (tid == 0) sAff = 0;
      __syncthreads();
      bool aff = (m_run[0] < -5.0e8f) || (m_run[1] < -5.0e8f) ||
                 (m_run[2] < -5.0e8f) || (m_run[3] < -5.0e8f);
      if (aff) sAff = 1;
      __syncthreads();
    }
  }

  #pragma unroll
  for (int r = 0; r < 4; ++r) {
    float inv = 1.0f / l_run[r];
    float* op = O + ((size_t)bh * Ss + qi0 + r) * Dd + l15;
    #pragma unroll
    for (int dt = 0; dt < 8; ++dt) op[dt * 16] = oacc[dt][r] * inv;
  }
}

extern "C" void kernel_launch(void* const* d_in, const int* in_sizes, int n_in,
                              void* d_out, int out_size, void* d_ws, size_t ws_size,
                              hipStream_t stream) {
  const float* q = (const float*)d_in[0];
  const float* k = (const float*)d_in[1];
  const float* v = (const float*)d_in[2];
  const int* mask = (const int*)d_in[3];
  float* out = (float*)d_out;

  const size_t need = (size_t)2 * NELEM * sizeof(u16) + (size_t)MASKN * sizeof(float);
  if (ws_size >= need) {
    u16* Kp = (u16*)d_ws;
    u16* Vp = Kp + NELEM;
    float* Mg = (float*)(Vp + NELEM);
    prep_kv<<<dim3(64 * NT), 256, 0, stream>>>(k, v, mask, Kp, Vp, Mg);
    attn_fwd<<<dim3(64 * NQT), 512, 0, stream>>>(q, Kp, Vp, Mg, out);
  } else {
    attn_fb<<<dim3(NT, 64), 256, 0, stream>>>(q, k, v, mask, out);
  }
}

// Round 9
// 210.812 us; speedup vs baseline: 1.6133x; 1.0059x over previous
//
#include <hip/hip_runtime.h>

typedef unsigned short u16;
typedef unsigned int   u32;
typedef __attribute__((ext_vector_type(8))) short  short8;   // 8 x bf16
typedef __attribute__((ext_vector_type(4))) float  floatx4;

#define CNEG  (-1.4426950408889634e9f)   // -1e9 * log2(e)  (exp2 domain)
#define QSCL  (0.12753129020334545f)     // (1/sqrt(128)) * log2(e)
#define NEGF  (-1000000000.0f)           // fallback kernel (exp domain)
#define DEFER_THR 8.0f

__device__ __forceinline__ u16 f2bf(float x) {            // f32 -> bf16 RNE
  u32 u = __builtin_bit_cast(u32, x);
  u += 0x7fffu + ((u >> 16) & 1u);
  return (u16)(u >> 16);
}
__device__ __forceinline__ u32 cvtpk(float lo, float hi) { // 2xf32 -> packed bf16
  u32 r;
  asm("v_cvt_pk_bf16_f32 %0, %1, %2" : "=v"(r) : "v"(lo), "v"(hi));
  return r;
}

// swizzles for the fallback kernel (ushort index space)
__device__ __forceinline__ int swzK(int r, int c)  { return r * 128 + (c ^ ((r & 7) << 3)); }
__device__ __forceinline__ int svb(int d)          { return ((d & 7) ^ ((d >> 2) & 7)) << 3; }
__device__ __forceinline__ int swzV(int d, int kv) { return d * 64 + (kv ^ svb(d)); }
// K-row permutation: slot -> source kv.  bits [b5 b4 | b3 b2 | b1 b0] -> [b5 | b3 b2 | b4 | b1 b0]
// Makes QK's C/D quads coincide with PV's K=32 B-fragment layout (no cross-lane redistribution).
__device__ __forceinline__ int sigma(int r) {
  return (r & 0x20) | ((r & 0xC) << 1) | ((r & 0x10) >> 2) | (r & 3);
}

__device__ __forceinline__ void gld16(const void* g, void* l) {
  __builtin_amdgcn_global_load_lds(
      (const __attribute__((address_space(1))) u32*)g,
      (__attribute__((address_space(3))) u32*)l, 16, 0, 0);
}

constexpr int Hh = 16, Ss = 2048, Dd = 128;
constexpr int QBLK = 128, KVBLK = 64;     // 8 waves x 16 q-rows
constexpr int NT = Ss / KVBLK;            // 32 kv tiles
constexpr int NQT = Ss / QBLK;            // 16 q tiles
constexpr int TILE = KVBLK * Dd;          // 8192 elements per tile
constexpr int NELEM = 4 * Hh * Ss * Dd;   // 16777216 per tensor
constexpr int MASKN = 4 * Ss;             // 8192 mask entries

// ---------------- prep: K,V -> bf16 FRAGMENT-LINEAR tiles; mask -> float CNEG-adds ----------------
// Both K and V tiles are stored as 16 fragments x 64 lanes x 8 bf16, so the main kernel's
// ds_read_b128 is lane*16B + compile-time offset (fully contiguous, conflict-free, no addr math).
__global__ __launch_bounds__(256) void prep_kv(const float* __restrict__ K,
                                               const float* __restrict__ V,
                                               const int* __restrict__ MSK,
                                               u16* __restrict__ Kp, u16* __restrict__ Vp,
                                               float* __restrict__ Mg) {
  __shared__ u16 Vl[KVBLK * 132];
  const int blk = blockIdx.x, tid = threadIdx.x;   // blk = bh*32 + t
  const float* kg = K + (size_t)blk * TILE;
  const float* vg = V + (size_t)blk * TILE;
  u16* kp = Kp + (size_t)blk * TILE;
  u16* vp = Vp + (size_t)blk * TILE;

  if (blk < MASKN / 256) {                         // mask -> exp2-domain additive floats
    int i = blk * 256 + tid;
    Mg[i] = MSK[i] ? 0.0f : CNEG;
  }

  // K: fragment-linear, sigma row mapping.  frag f = kt*4+kc; lane ln holds
  // Kslot[kt*16+(ln&15)][kc*32+(ln>>4)*8+i], Kslot[r] = Ksrc[sigma(r)].
  #pragma unroll
  for (int it = 0; it < 4; ++it) {
    int ch = tid + it * 256;             // chunk 0..1023
    int f = ch >> 6, ln = ch & 63;
    int kt = f >> 2, kc = f & 3;
    int kv = sigma(kt * 16 + (ln & 15));
    int d0 = kc * 32 + (ln >> 4) * 8;
    const float* s = kg + kv * 128 + d0;
    float4 a = *(const float4*)s, bq = *(const float4*)(s + 4);
    union { short8 v; u16 h[8]; } u;
    u.h[0] = f2bf(a.x);  u.h[1] = f2bf(a.y);  u.h[2] = f2bf(a.z);  u.h[3] = f2bf(a.w);
    u.h[4] = f2bf(bq.x); u.h[5] = f2bf(bq.y); u.h[6] = f2bf(bq.z); u.h[7] = f2bf(bq.w);
    *(short8*)(kp + ch * 8) = u.v;
  }
  // V: coalesced read -> LDS bf16 [kv][d]
  #pragma unroll
  for (int it = 0; it < 8; ++it) {
    int e = (tid + it * 256) * 4;
    int r = e >> 7, c = e & 127;
    float4 a = *(const float4*)(vg + e);
    uint2 w;
    w.x = (u32)f2bf(a.x) | ((u32)f2bf(a.y) << 16);
    w.y = (u32)f2bf(a.z) | ((u32)f2bf(a.w) << 16);
    *(uint2*)&Vl[r * 132 + c] = w;
  }
  __syncthreads();
  // V out: fragment-linear.  frag f = dt*2+kc; lane ln holds V^T[dt*16+(ln&15)][kc*32+(ln>>4)*8+i].
  #pragma unroll
  for (int it = 0; it < 4; ++it) {
    int f = tid + it * 256;              // 0..1023
    int ln = f & 63, seg = f >> 6;       // seg = dt*2 + kc
    int kc = seg & 1, dt = seg >> 1;
    int d = dt * 16 + (ln & 15);
    int kv0 = kc * 32 + (ln >> 4) * 8;
    union { short8 v; u16 h[8]; } u;
    #pragma unroll
    for (int i = 0; i < 8; ++i) u.h[i] = Vl[(kv0 + i) * 132 + d];
    *(short8*)(vp + f * 8) = u.v;
  }
}

// ---------------- main: 8 waves / 128 q-rows, fragment-linear LDS, shuffle-free steady-state softmax ----------------
__global__ __launch_bounds__(512, 4) void attn_fwd(const float* __restrict__ Q,
                                                   const u16* __restrict__ Kp,
                                                   const u16* __restrict__ Vp,
                                                   const float* __restrict__ Mg,
                                                   float* __restrict__ O) {
  __shared__ u16 Kl[2][TILE];              // 32 KB
  __shared__ u16 Vt[2][TILE];              // 32 KB -> 64KB total, 2 blocks/CU, 16 waves/CU
  __shared__ int sAff;

  const int tid = threadIdx.x, lane = tid & 63, wid = tid >> 6;
  const int l15 = lane & 15, lg = lane >> 4;
  const int id = blockIdx.x;                       // bijective XCD swizzle (1024 % 8 == 0)
  const int wg = (id & 7) * 128 + (id >> 3);
  const int bh = wg >> 4, qt = 15 - (wg & 15), b = bh >> 4;  // longest-first within chunk
  const int qbase = qt * QBLK;
  const int qi = qbase + wid * 16 + l15;           // this lane's single q-row
  const int dtl = 2 * qt + 1;                      // last causal kv-tile for this block

  if (tid == 0) sAff = 0;

  // Q fragments (B operand): col=q=l15, k=lg*8+i
  const float* qg = Q + ((size_t)bh * Ss + qi) * Dd + lg * 8;
  short8 qf[4];
  #pragma unroll
  for (int kc = 0; kc < 4; ++kc) {
    float4 x0 = *(const float4*)(qg + kc * 32);
    float4 x1 = *(const float4*)(qg + kc * 32 + 4);
    union { short8 v; u16 h[8]; } u;
    u.h[0] = f2bf(x0.x * QSCL); u.h[1] = f2bf(x0.y * QSCL);
    u.h[2] = f2bf(x0.z * QSCL); u.h[3] = f2bf(x0.w * QSCL);
    u.h[4] = f2bf(x1.x * QSCL); u.h[5] = f2bf(x1.y * QSCL);
    u.h[6] = f2bf(x1.z * QSCL); u.h[7] = f2bf(x1.w * QSCL);
    qf[kc] = u.v;
  }

  const size_t tb = (size_t)bh * NT;
  auto stage = [&](int buf, int t) {       // 8 waves cover 16KB K + 16KB V: 4 gld16/thread
    const char* gk = (const char*)(Kp + (tb + t) * TILE) + wid * 1024 + lane * 16;
    const char* gv = (const char*)(Vp + (tb + t) * TILE) + wid * 1024 + lane * 16;
    char* lk = (char*)&Kl[buf][0] + wid * 1024;    // wave-uniform dest base
    char* lv = (char*)&Vt[buf][0] + wid * 1024;
    #pragma unroll
    for (int i = 0; i < 2; ++i) {
      gld16(gk + i * 8192, lk + i * 8192);
      gld16(gv + i * 8192, lv + i * 8192);
    }
  };

  float m_run = -3.0e38f, l_part = 0.0f;   // l_part: per-lane partial row-sum (reduced in epilogue)
  floatx4 oacc[8];
  const floatx4 vzero = {0.f, 0.f, 0.f, 0.f};
  #pragma unroll
  for (int dt = 0; dt < 8; ++dt) oacc[dt] = vzero;

  stage(0, 0);
  __syncthreads();

  int cur = 0;
  bool staged = true;
  for (int t = 0; t < NT; ++t) {
    if (t > dtl && !sAff) break;           // future tiles only for the padding-quirk rows
    if (!staged) { stage(cur, t); __syncthreads(); }
    const bool pref = (t + 1 <= dtl);
    if (pref) stage(cur ^ 1, t + 1);

    const int kvbase = t * KVBLK;
    // slot (kt,lg,r) holds score for kv = kvbase + 32*(kt>>1) + lg*8 + 4*(kt&1) + r
    float4 md[4];
    #pragma unroll
    for (int kt = 0; kt < 4; ++kt) {
      const int kvs = kvbase + ((kt >> 1) << 5) + lg * 8 + ((kt & 1) << 2);
      md[kt] = *(const float4*)(Mg + b * Ss + kvs);
    }

    // S^T = K . Q^T  -- fragment-linear K: lane*16B + immediate, conflict-free
    const u16* kbase = &Kl[cur][lane * 8];
    floatx4 sacc[4];
    #pragma unroll
    for (int kt = 0; kt < 4; ++kt) sacc[kt] = vzero;
    __builtin_amdgcn_s_setprio(1);
    #pragma unroll
    for (int kt = 0; kt < 4; ++kt) {
      #pragma unroll
      for (int kc = 0; kc < 4; ++kc) {
        short8 kf = *(const short8*)&kbase[(kt * 4 + kc) * 512];
        sacc[kt] = __builtin_amdgcn_mfma_f32_16x16x32_bf16(kf, qf[kc], sacc[kt], 0, 0, 0);
      }
    }
    __builtin_amdgcn_s_setprio(0);

    // scores + masks (additive in f32, matching reference rounding)
    float p[4][4];
    #pragma unroll
    for (int kt = 0; kt < 4; ++kt) {
      p[kt][0] = sacc[kt][0] + md[kt].x;
      p[kt][1] = sacc[kt][1] + md[kt].y;
      p[kt][2] = sacc[kt][2] + md[kt].z;
      p[kt][3] = sacc[kt][3] + md[kt].w;
    }
    // causal: wave-uniform skip when tile fully visible for this wave's 16 rows
    if (kvbase + KVBLK - 1 >= qbase + wid * 16) {
      #pragma unroll
      for (int kt = 0; kt < 4; ++kt) {
        const int kvs = kvbase + ((kt >> 1) << 5) + lg * 8 + ((kt & 1) << 2);
        #pragma unroll
        for (int r = 0; r < 4; ++r)
          if (kvs + r > qi) p[kt][r] += CNEG;
      }
    }

    // local row max (per-thread tree, no shuffles)
    float pmax = p[0][0];
    #pragma unroll
    for (int kt = 0; kt < 4; ++kt)
      #pragma unroll
      for (int r = 0; r < 4; ++r) pmax = fmaxf(pmax, p[kt][r]);

    // defer-max: common path needs NO cross-lane ops at all
    float mn = m_run;
    if (!__all(pmax <= m_run + DEFER_THR)) {
      pmax = fmaxf(pmax, __shfl_xor(pmax, 16, 64));
      pmax = fmaxf(pmax, __shfl_xor(pmax, 32, 64));
      mn = fmaxf(m_run, pmax);
      const float alpha = exp2f(m_run - mn);
      m_run = mn;
      l_part *= alpha;
      #pragma unroll
      for (int dt = 0; dt < 8; ++dt)
        #pragma unroll
        for (int r = 0; r < 4; ++r) oacc[dt][r] *= alpha;
    }

    #pragma unroll
    for (int kt = 0; kt < 4; ++kt)
      #pragma unroll
      for (int r = 0; r < 4; ++r) {
        const float pv = exp2f(p[kt][r] - mn);
        p[kt][r] = pv;
        l_part += pv;
      }

    // P fragments: sigma-permuted K rows make sacc quads pack DIRECTLY into the
    // K=32 B-operand layout — 8 cvt_pk, no cross-lane redistribution.
    union { short8 v; u32 w[4]; } pf[2];
    #pragma unroll
    for (int kc = 0; kc < 2; ++kc) {
      pf[kc].w[0] = cvtpk(p[2 * kc][0],     p[2 * kc][1]);
      pf[kc].w[1] = cvtpk(p[2 * kc][2],     p[2 * kc][3]);
      pf[kc].w[2] = cvtpk(p[2 * kc + 1][0], p[2 * kc + 1][1]);
      pf[kc].w[3] = cvtpk(p[2 * kc + 1][2], p[2 * kc + 1][3]);
    }

    // O^T += V^T . P^T ; V fragment-linear: base + immediate offsets, conflict-free b128
    const u16* vbase = &Vt[cur][lane * 8];
    __builtin_amdgcn_s_setprio(1);
    #pragma unroll
    for (int kc = 0; kc < 2; ++kc) {
      #pragma unroll
      for (int dt = 0; dt < 8; ++dt) {
        short8 vf = *(const short8*)&vbase[(dt * 2 + kc) * 512];
        oacc[dt] = __builtin_amdgcn_mfma_f32_16x16x32_bf16(vf, pf[kc].v, oacc[dt], 0, 0, 0);
      }
    }
    __builtin_amdgcn_s_setprio(0);

    if (t == dtl) {
      if (m_run < -1.0e9f) sAff = 1;       // fully-masked visible prefix (benign race)
    }
    __syncthreads();
    staged = pref;
    cur ^= 1;
  }

  // epilogue: reduce l across the 4 lg lanes of each q-row, then O[qi][d] = oacc/l
  float l_run = l_part;
  l_run += __shfl_xor(l_run, 16, 64);
  l_run += __shfl_xor(l_run, 32, 64);
  const float inv = 1.0f / l_run;
  float* orow = O + ((size_t)bh * Ss + qi) * Dd;
  #pragma unroll
  for (int dt = 0; dt < 8; ++dt) {
    float4 o4;
    o4.x = oacc[dt][0] * inv; o4.y = oacc[dt][1] * inv;
    o4.z = oacc[dt][2] * inv; o4.w = oacc[dt][3] * inv;
    *(float4*)(orow + dt * 16 + lg * 4) = o4;
  }
}

// ---------------- fallback (round-2 self-contained kernel) if d_ws is too small ----------------
__device__ __forceinline__ int swzPf(int row, int col) { return row * 64 + (col ^ ((row & 7) << 3)); }

__global__ __launch_bounds__(256) void attn_fb(
    const float* __restrict__ Q, const float* __restrict__ K,
    const float* __restrict__ V, const int* __restrict__ MSK,
    float* __restrict__ O)
{
  __shared__ u16 Kls[KVBLK * Dd];
  __shared__ u16 Vts[Dd * KVBLK];
  __shared__ u16 Pls[4][16 * KVBLK];
  __shared__ int sAff;

  const int tid = threadIdx.x, lane = tid & 63, wid = tid >> 6;
  const int l15 = lane & 15, lg = lane >> 4;
  const int qt = blockIdx.x, bh = blockIdx.y, b = bh >> 4;
  const int qbase = qt * 64;
  const float scale = 0.08838834764831845f;

  const int qrowA = qbase + wid * 16 + l15;
  const float* qg = Q + ((size_t)bh * Ss + qrowA) * Dd + lg * 8;
  short8 qf[4];
  #pragma unroll
  for (int kc = 0; kc < 4; ++kc) {
    float4 x0 = *(const float4*)(qg + kc * 32);
    float4 x1 = *(const float4*)(qg + kc * 32 + 4);
    union { short8 v; u16 h[8]; } u;
    u.h[0] = f2bf(x0.x * scale); u.h[1] = f2bf(x0.y * scale);
    u.h[2] = f2bf(x0.z * scale); u.h[3] = f2bf(x0.w * scale);
    u.h[4] = f2bf(x1.x * scale); u.h[5] = f2bf(x1.y * scale);
    u.h[6] = f2bf(x1.z * scale); u.h[7] = f2bf(x1.w * scale);
    qf[kc] = u.v;
  }

  float m_run[4], l_run[4];
  floatx4 oacc[8];
  const floatx4 vzero = {0.f, 0.f, 0.f, 0.f};
  #pragma unroll
  for (int r = 0; r < 4; ++r) { m_run[r] = -3.0e38f; l_run[r] = 0.0f; }
  #pragma unroll
  for (int dt = 0; dt < 8; ++dt) oacc[dt] = vzero;
  const int qi0 = qbase + wid * 16 + lg * 4;

  for (int t = 0; t < NT; ++t) {
    if (t > blockIdx.x && !sAff) break;
    const int kvbase = t * KVBLK;
    const float* kg = K + ((size_t)bh * Ss + kvbase) * Dd;
    const float* vg = V + ((size_t)bh * Ss + kvbase) * Dd;
    #pragma unroll
    for (int it = 0; it < 8; ++it) {
      int e = (tid + it * 256) * 4;
      int r0 = e >> 7, c0 = e & 127;
      float4 x = *(const float4*)(kg + e);
      uint2 hk;
      hk.x = (u32)f2bf(x.x) | ((u32)f2bf(x.y) << 16);
      hk.y = (u32)f2bf(x.z) | ((u32)f2bf(x.w) << 16);
      *(uint2*)&Kls[swzK(r0, c0)] = hk;
      float4 y = *(const float4*)(vg + e);
      u16 hv[4] = { f2bf(y.x), f2bf(y.y), f2bf(y.z), f2bf(y.w) };
      #pragma unroll
      for (int j = 0; j < 4; ++j) Vts[swzV(c0 + j, r0)] = hv[j];
    }
    __syncthreads();

    float madd[4];
    #pragma unroll
    for (int kt = 0; kt < 4; ++kt)
      madd[kt] = MSK[b * Ss + kvbase + kt * 16 + l15] ? 0.0f : NEGF;

    floatx4 sacc[4];
    #pragma unroll
    for (int kt = 0; kt < 4; ++kt) sacc[kt] = vzero;
    #pragma unroll
    for (int kt = 0; kt < 4; ++kt) {
      const int krow = kt * 16 + l15;
      #pragma unroll
      for (int kc = 0; kc < 4; ++kc) {
        short8 kf = *(const short8*)&Kls[swzK(krow, kc * 32 + lg * 8)];
        sacc[kt] = __builtin_amdgcn_mfma_f32_16x16x32_bf16(qf[kc], kf, sacc[kt], 0, 0, 0);
      }
    }

    float mnew[4];
    #pragma unroll
    for (int r = 0; r < 4; ++r) mnew[r] = m_run[r];
    #pragma unroll
    for (int kt = 0; kt < 4; ++kt) {
      const int kvj = kvbase + kt * 16 + l15;
      #pragma unroll
      for (int r = 0; r < 4; ++r) {
        float s = sacc[kt][r] + madd[kt];
        if (kvj > qi0 + r) s += NEGF;
        sacc[kt][r] = s;
        mnew[r] = fmaxf(mnew[r], s);
      }
    }
    #pragma unroll
    for (int off = 1; off < 16; off <<= 1) {
      #pragma unroll
      for (int r = 0; r < 4; ++r)
        mnew[r] = fmaxf(mnew[r], __shfl_xor(mnew[r], off, 64));
    }
    float alpha[4], psum[4];
    #pragma unroll
    for (int r = 0; r < 4; ++r) {
      alpha[r] = __expf(m_run[r] - mnew[r]);
      m_run[r] = mnew[r];
      psum[r] = 0.f;
    }
    #pragma unroll
    for (int kt = 0; kt < 4; ++kt) {
      #pragma unroll
      for (int r = 0; r < 4; ++r) {
        float p = __expf(sacc[kt][r] - mnew[r]);
        psum[r] += p;
        Pls[wid][swzPf(lg * 4 + r, kt * 16 + l15)] = f2bf(p);
      }
    }
    #pragma unroll
    for (int off = 1; off < 16; off <<= 1) {
      #pragma unroll
      for (int r = 0; r < 4; ++r)
        psum[r] += __shfl_xor(psum[r], off, 64);
    }
    #pragma unroll
    for (int r = 0; r < 4; ++r) l_run[r] = l_run[r] * alpha[r] + psum[r];
    #pragma unroll
    for (int dt = 0; dt < 8; ++dt) {
      #pragma unroll
      for (int r = 0; r < 4; ++r) oacc[dt][r] *= alpha[r];
    }
    #pragma unroll
    for (int kc = 0; kc < 2; ++kc) {
      short8 pfr = *(const short8*)&Pls[wid][swzPf(l15, kc * 32 + lg * 8)];
      #pragma unroll
      for (int dt = 0; dt < 8; ++dt) {
        short8 vf = *(const short8*)&Vts[swzV(dt * 16 + l15, kc * 32 + lg * 8)];
        oacc[dt] = __builtin_amdgcn_mfma_f32_16x16x32_bf16(pfr, vf, oacc[dt], 0, 0, 0);
      }
    }
    __syncthreads();

    if (t == blockIdx.x) {
      if (tid == 0) sAff = 0;
      __syncthreads();
      bool aff = (m_run[0] < -5.0e8f) || (m_run[1] < -5.0e8f) ||
                 (m_run[2] < -5.0e8f) || (m_run[3] < -5.0e8f);
      if (aff) sAff = 1;
      __syncthreads();
    }
  }

  #pragma unroll
  for (int r = 0; r < 4; ++r) {
    float inv = 1.0f / l_run[r];
    float* op = O + ((size_t)bh * Ss + qi0 + r) * Dd + l15;
    #pragma unroll
    for (int dt = 0; dt < 8; ++dt) op[dt * 16] = oacc[dt][r] * inv;
  }
}

extern "C" void kernel_launch(void* const* d_in, const int* in_sizes, int n_in,
                              void* d_out, int out_size, void* d_ws, size_t ws_size,
                              hipStream_t stream) {
  const float* q = (const float*)d_in[0];
  const float* k = (const float*)d_in[1];
  const float* v = (const float*)d_in[2];
  const int* mask = (const int*)d_in[3];
  float* out = (float*)d_out;

  const size_t need = (size_t)2 * NELEM * sizeof(u16) + (size_t)MASKN * sizeof(float);
  if (ws_size >= need) {
    u16* Kp = (u16*)d_ws;
    u16* Vp = Kp + NELEM;
    float* Mg = (float*)(Vp + NELEM);
    prep_kv<<<dim3(64 * NT), 256, 0, stream>>>(k, v, mask, Kp, Vp, Mg);
    attn_fwd<<<dim3(64 * NQT), 512, 0, stream>>>(q, Kp, Vp, Mg, out);
  } else {
    attn_fb<<<dim3(NT, 64), 256, 0, stream>>>(q, k, v, mask, out);
  }
}